// Round 5
// baseline (1277.551 us; speedup 1.0000x reference)
//
#include <hip/hip_runtime.h>
#include <hip/hip_bf16.h>

typedef __attribute__((ext_vector_type(8))) short short8;     // 8 bf16 (4 VGPRs) MFMA A/B frag
typedef __attribute__((ext_vector_type(4))) float f32x4;      // 16x16 MFMA C/D frag
typedef __attribute__((ext_vector_type(16))) float f32x16;    // 32x32 MFMA C/D frag
typedef __attribute__((ext_vector_type(4))) unsigned short u16x4;
typedef __attribute__((ext_vector_type(4))) unsigned int u32x4;

#define MFMA16(a, b, c) __builtin_amdgcn_mfma_f32_16x16x32_bf16((a), (b), (c), 0, 0, 0)
#define MFMA32(a, b, c) __builtin_amdgcn_mfma_f32_32x32x16_bf16((a), (b), (c), 0, 0, 0)

__device__ __forceinline__ unsigned short f2bf(float f) {
    union { float f; unsigned u; } v; v.f = f;
    return (unsigned short)((v.u + 0x7fffu + ((v.u >> 16) & 1u)) >> 16);
}

__device__ __forceinline__ unsigned cvtpk(float lo, float hi_) {
    unsigned r;
    asm volatile("v_cvt_pk_bf16_f32 %0, %1, %2" : "=v"(r) : "v"(lo), "v"(hi_));
    return r;
}

// ---------------------------------------------------------------- cast X -> bf16
__global__ void cast_x_kernel(const float* __restrict__ x, ushort* __restrict__ y) {
    int i = blockIdx.x * blockDim.x + threadIdx.x;      // one float4 per thread, exact grid
    float4 v = ((const float4*)x)[i];
    u16x4 o = { f2bf(v.x), f2bf(v.y), f2bf(v.z), f2bf(v.w) };
    *(u16x4*)(y + (size_t)i * 4) = o;
}

// ------------------------------------------- W [K][N] f32 -> WT [N][K] bf16
__global__ void transpose_cast_kernel(const float* __restrict__ W, ushort* __restrict__ WT,
                                      int K, int N) {
    __shared__ ushort t[64][66];                        // 66: odd word stride, conflict-free
    int n0 = blockIdx.x * 64, k0 = blockIdx.y * 64;
    int tn = threadIdx.x & 63, tg = threadIdx.x >> 6;
#pragma unroll
    for (int i = 0; i < 16; ++i) {
        int k = tg * 16 + i;
        t[tn][k] = f2bf(W[(size_t)(k0 + k) * N + n0 + tn]);
    }
    __syncthreads();
#pragma unroll
    for (int i = 0; i < 16; ++i) {
        int nn = tg * 16 + i;
        WT[(size_t)(n0 + nn) * K + k0 + tn] = t[nn][tn];
    }
}

// ---------------------------------------------------------------- GEMM C = A @ BT^T
// A [M][K] bf16 row-major, BT [N][K] bf16 (n-major). 128x128 tile, BK=64, 4 waves.
// MODE 0: QKV epilogue -> scatter Q (prescaled), K, VT (transposed V), bf16.
// MODE 1: proj epilogue -> Out fp32 [M][N].
#define QSCALE 0.18033688011112042f   /* 0.125 * log2(e) */

template <int MODE>
__global__ __launch_bounds__(256)
void gemm_bt_kernel(const ushort* __restrict__ A, const ushort* __restrict__ BT,
                    const float* __restrict__ bias,
                    ushort* __restrict__ Qb, ushort* __restrict__ Kb,
                    ushort* __restrict__ VT, float* __restrict__ Out,
                    int M, int N, int K) {
    __shared__ ushort Asm[128 * 64];
    __shared__ ushort Bsm[128 * 64];
    const int lane = threadIdx.x & 63;
    const int wv = threadIdx.x >> 6;
    const int l15 = lane & 15, lg = lane >> 4;
    const int rm = (wv >> 1) * 64, cn = (wv & 1) * 64;  // wave's 64x64 sub-tile
    const int row0 = blockIdx.y * 128, col0 = blockIdx.x * 128;

    const char* Agb = (const char*)(A + (size_t)row0 * K);
    const char* Bgb = (const char*)(BT + (size_t)col0 * K);
    const size_t rowbytes = (size_t)K * 2;

    f32x4 acc[4][4];
#pragma unroll
    for (int mi = 0; mi < 4; ++mi)
#pragma unroll
        for (int ni = 0; ni < 4; ++ni) acc[mi][ni] = f32x4{0.f, 0.f, 0.f, 0.f};

    const int grow_l = (lane >> 3);          // 0..7 within 8-row chunk
    const int gcol_l = (lane & 7) * 16;      // byte within 128B row

    for (int k0 = 0; k0 < K; k0 += 64) {
#pragma unroll
        for (int c = 0; c < 4; ++c) {
            int chunk = wv * 4 + c;                       // 16 chunks of 1KB
            size_t go = (size_t)(chunk * 8 + grow_l) * rowbytes + (size_t)k0 * 2 + gcol_l;
            int lo = chunk * 1024 + lane * 16;
            __builtin_amdgcn_global_load_lds(
                (const __attribute__((address_space(1))) void*)(Agb + go),
                (__attribute__((address_space(3))) void*)((char*)Asm + lo), 16, 0, 0);
            __builtin_amdgcn_global_load_lds(
                (const __attribute__((address_space(1))) void*)(Bgb + go),
                (__attribute__((address_space(3))) void*)((char*)Bsm + lo), 16, 0, 0);
        }
        __syncthreads();
#pragma unroll
        for (int ks = 0; ks < 2; ++ks) {
            short8 af[4], bf[4];
#pragma unroll
            for (int mi = 0; mi < 4; ++mi)
                af[mi] = *(const short8*)&Asm[(rm + mi * 16 + l15) * 64 + ks * 32 + lg * 8];
#pragma unroll
            for (int ni = 0; ni < 4; ++ni)
                bf[ni] = *(const short8*)&Bsm[(cn + ni * 16 + l15) * 64 + ks * 32 + lg * 8];
#pragma unroll
            for (int mi = 0; mi < 4; ++mi)
#pragma unroll
                for (int ni = 0; ni < 4; ++ni)
                    acc[mi][ni] = MFMA16(af[mi], bf[ni], acc[mi][ni]);
        }
        __syncthreads();
    }

    // Epilogue. D layout: lane holds D[(lg)*4+j][l15] (row=M dim, col=N dim).
    if (MODE == 0) {
        const int sect = col0 >> 10;   // 0=q 1=k 2=v, uniform per block (128 | 1024)
#pragma unroll
        for (int ni = 0; ni < 4; ++ni) {
            int col = col0 + cn + ni * 16 + l15;
            float bv = bias[col];
            int dcol = col & 1023, h = dcol >> 6, dd = dcol & 63;
#pragma unroll
            for (int mi = 0; mi < 4; ++mi) {
                int mrow0 = row0 + rm + mi * 16 + lg * 4;
                if (sect == 2) {
                    int b = mrow0 >> 11, s = mrow0 & 2047;   // 4 consecutive s, same b
                    u16x4 o;
#pragma unroll
                    for (int j = 0; j < 4; ++j) o[j] = f2bf(acc[mi][ni][j] + bv);
                    *(u16x4*)&VT[((size_t)((b << 4) + h) * 64 + dd) * 2048 + s] = o;
                } else {
                    ushort* dst = sect ? Kb : Qb;
                    float sc = sect ? 1.f : QSCALE;
#pragma unroll
                    for (int j = 0; j < 4; ++j) {
                        int tok = mrow0 + j;
                        int b = tok >> 11, s = tok & 2047;
                        dst[((size_t)((b << 4) + h) * 2048 + s) * 64 + dd] =
                            f2bf((acc[mi][ni][j] + bv) * sc);
                    }
                }
            }
        }
    } else {
#pragma unroll
        for (int ni = 0; ni < 4; ++ni) {
            int col = col0 + cn + ni * 16 + l15;
            float bv = bias[col];
#pragma unroll
            for (int mi = 0; mi < 4; ++mi) {
                int mrow0 = row0 + rm + mi * 16 + lg * 4;
#pragma unroll
                for (int j = 0; j < 4; ++j)
                    Out[(size_t)(mrow0 + j) * N + col] = acc[mi][ni][j] + bv;
            }
        }
    }
}

// ---------------------------------------------------------------- causal flash attention v4
// 1 WAVE PER BLOCK, NO LDS, NO BARRIERS. K/V per head (512KB) is L2-resident
// (4 heads pinned per XCD), so LDS staging is pure overhead (guide m169).
// Each wave owns 32 q-rows; KVBLK=64; K/V MFMA fragments read DIRECTLY from
// global (same addresses staging used). Swapped QK^T: S^T = mfma(K,Q), lane
// owns q-row lane&31. P re-frag in regs via cvt_pk + permlane32_swap (T12,
// verified round 4). Defer-max THR=8 (T13). setprio around MFMA (T5, m191).
// Diagonal chunk: even tiles skip the fully-masked upper half-tile.
// Grid: 2048 blocks = 8 xcd x (4 heads x 64 tiles), heavy-first (LPT).
__global__ __launch_bounds__(64, 3)
void attn_kernel(const ushort* __restrict__ Qb, const ushort* __restrict__ Kb,
                 const ushort* __restrict__ VT, ushort* __restrict__ CTX) {
    const int lane = threadIdx.x;                        // 0..63
    const int l31 = lane & 31;
    const int hi = lane >> 5;                            // 0/1
    const int id = blockIdx.x;
    const int xcd = id & 7, jj = id >> 3;                // jj 0..255
    const int bh = (xcd << 2) + (jj >> 6);               // 4 heads per XCD
    const int t = 63 - (jj & 63);                        // 32-row q-tile, heavy first
    const int q0 = t * 32;
    const int qrow = q0 + l31;

    const ushort* Qh = Qb + (size_t)bh * 2048 * 64;
    const ushort* Kh = Kb + (size_t)bh * 2048 * 64;
    const ushort* Vh = VT + (size_t)bh * 64 * 2048;

    // Q fragments (B-operand of mfma(K,Q)): Q[qrow][dc*16 + hi*8 .. +7]
    short8 qf[4];
#pragma unroll
    for (int dc = 0; dc < 4; ++dc)
        qf[dc] = *(const short8*)&Qh[(size_t)qrow * 64 + dc * 16 + hi * 8];

    const int nc = (t >> 1) + 1;                         // 64-key chunks
    const bool teven = (t & 1) == 0;

    float mrun = -1e30f, lsum = 0.f;
    f32x16 acc0, acc1;                                   // ctx^T d 0..31 / 32..63
#pragma unroll
    for (int r = 0; r < 16; ++r) { acc0[r] = 0.f; acc1[r] = 0.f; }

    for (int c = 0; c < nc; ++c) {
        const int kb = c * 64;
        const bool lastc = (c == nc - 1);
        const bool only0 = lastc && teven;               // upper 32 keys fully masked

        // ---- K fragments (A-operand): K[kb + {0,32} + l31][dc*16 + hi*8]
        const ushort* kbase = Kh + (size_t)(kb + l31) * 64 + hi * 8;
        short8 kf0[4], kf1[4];
#pragma unroll
        for (int dc = 0; dc < 4; ++dc) kf0[dc] = *(const short8*)(kbase + dc * 16);
        if (!only0) {
#pragma unroll
            for (int dc = 0; dc < 4; ++dc) kf1[dc] = *(const short8*)(kbase + 2048 + dc * 16);
        }
        // ---- V fragments (A-operand of PV): VT[{0,32}+l31][kb + j*16 + hi*8]
        const ushort* vbase = Vh + (size_t)l31 * 2048 + kb + hi * 8;
        short8 vf0[4], vf1[4];
        {
            const int nj = only0 ? 2 : 4;
            for (int j = 0; j < nj; ++j) {
                vf0[j] = *(const short8*)(vbase + j * 16);
                vf1[j] = *(const short8*)(vbase + 32 * 2048 + j * 16);
            }
        }

        // ---- QK^T
        f32x16 st0, st1;
#pragma unroll
        for (int r = 0; r < 16; ++r) { st0[r] = 0.f; st1[r] = 0.f; }
        __builtin_amdgcn_s_setprio(1);
#pragma unroll
        for (int dc = 0; dc < 4; ++dc) st0 = MFMA32(kf0[dc], qf[dc], st0);
        if (!only0) {
#pragma unroll
            for (int dc = 0; dc < 4; ++dc) st1 = MFMA32(kf1[dc], qf[dc], st1);
        }
        __builtin_amdgcn_s_setprio(0);

        // ---- causal mask (diagonal chunk only); key = base + (r&3) + 8*(r>>2)
        if (lastc) {
            if (teven) {                                  // diag in st0
                const int base0 = kb + (hi << 2);
#pragma unroll
                for (int r = 0; r < 16; ++r) {
                    int k0 = base0 + ((r & 3) + 8 * (r >> 2));
                    st0[r] = (k0 <= qrow) ? st0[r] : -1e30f;
                }
            } else {                                      // diag in st1 (st0 all valid)
                const int base1 = kb + 32 + (hi << 2);
#pragma unroll
                for (int r = 0; r < 16; ++r) {
                    int k1 = base1 + ((r & 3) + 8 * (r >> 2));
                    st1[r] = (k1 <= qrow) ? st1[r] : -1e30f;
                }
            }
        }

        // ---- online softmax (log2 domain), defer-max THR=8
        float tmax = st0[0];
#pragma unroll
        for (int r = 1; r < 16; ++r) tmax = fmaxf(tmax, st0[r]);
        if (!only0) {
#pragma unroll
            for (int r = 0; r < 16; ++r) tmax = fmaxf(tmax, st1[r]);
        }
        tmax = fmaxf(tmax, __shfl_xor(tmax, 32));        // partner holds other key-half

        if (!__all(tmax <= mrun + 8.0f)) {
            float mnew = fmaxf(mrun, tmax);
            float sc = exp2f(mrun - mnew);
#pragma unroll
            for (int r = 0; r < 16; ++r) { acc0[r] *= sc; acc1[r] *= sc; }
            lsum *= sc;
            mrun = mnew;
        }

        float tsum = 0.f;
#pragma unroll
        for (int r = 0; r < 16; ++r) { st0[r] = exp2f(st0[r] - mrun); tsum += st0[r]; }
        if (!only0) {
#pragma unroll
            for (int r = 0; r < 16; ++r) { st1[r] = exp2f(st1[r] - mrun); tsum += st1[r]; }
        }
        lsum += tsum;                                    // partner partial merged at end

        // ---- P re-frag in registers + PV (T12; verified round 4)
        // permlane32_swap: vdst[32+i] <-> vsrc[i]; lanes 0-31 receive in vsrc (pb),
        // lanes 32-63 receive in vdst (pa).
#define MAKE_PFRAG(st, kcL, out)                                                        \
    do {                                                                                \
        unsigned c00 = cvtpk(st[8 * kcL + 0], st[8 * kcL + 1]);                         \
        unsigned c01 = cvtpk(st[8 * kcL + 2], st[8 * kcL + 3]);                         \
        unsigned c10 = cvtpk(st[8 * kcL + 4], st[8 * kcL + 5]);                         \
        unsigned c11 = cvtpk(st[8 * kcL + 6], st[8 * kcL + 7]);                         \
        unsigned e0 = hi ? c00 : c10, e1 = hi ? c01 : c11;                              \
        unsigned pa0 = e0, pb0 = e0, pa1 = e1, pb1 = e1;                                \
        asm volatile("v_permlane32_swap_b32 %0, %1" : "+v"(pa0), "+v"(pb0));            \
        asm volatile("v_permlane32_swap_b32 %0, %1" : "+v"(pa1), "+v"(pb1));            \
        unsigned rec0 = hi ? pa0 : pb0;                                                 \
        unsigned rec1 = hi ? pa1 : pb1;                                                 \
        u32x4 fw;                                                                       \
        fw.x = hi ? rec0 : c00;                                                         \
        fw.y = hi ? rec1 : c01;                                                         \
        fw.z = hi ? c10 : rec0;                                                         \
        fw.w = hi ? c11 : rec1;                                                         \
        out = __builtin_bit_cast(short8, fw);                                           \
    } while (0)

        short8 pf;
        __builtin_amdgcn_s_setprio(1);
        MAKE_PFRAG(st0, 0, pf);
        acc0 = MFMA32(vf0[0], pf, acc0);
        acc1 = MFMA32(vf1[0], pf, acc1);
        MAKE_PFRAG(st0, 1, pf);
        acc0 = MFMA32(vf0[1], pf, acc0);
        acc1 = MFMA32(vf1[1], pf, acc1);
        if (!only0) {
            MAKE_PFRAG(st1, 0, pf);
            acc0 = MFMA32(vf0[2], pf, acc0);
            acc1 = MFMA32(vf1[2], pf, acc1);
            MAKE_PFRAG(st1, 1, pf);
            acc0 = MFMA32(vf0[3], pf, acc0);
            acc1 = MFMA32(vf1[3], pf, acc1);
        }
        __builtin_amdgcn_s_setprio(0);
#undef MAKE_PFRAG
    }

    lsum += __shfl_xor(lsum, 32);                        // merge partner halves
    const float inv = 1.f / lsum;
    const int b = bh >> 4, h = bh & 15;
    const size_t tokrow = ((size_t)b * 2048 + q0 + l31) * 1024 + (size_t)h * 64;

#define WRITE_DT(accv, dt)                                                              \
    do {                                                                                \
        _Pragma("unroll")                                                               \
        for (int q2 = 0; q2 < 4; ++q2) {                                                \
            int d0 = dt * 32 + 8 * q2 + (hi << 2);                                      \
            u16x4 o;                                                                    \
            _Pragma("unroll")                                                           \
            for (int j = 0; j < 4; ++j) o[j] = f2bf(accv[4 * q2 + j] * inv);            \
            *(u16x4*)&CTX[tokrow + d0] = o;                                             \
        }                                                                               \
    } while (0)

    WRITE_DT(acc0, 0);
    WRITE_DT(acc1, 1);
#undef WRITE_DT
}

// ----------------------------------------------------------------------------
extern "C" void kernel_launch(void* const* d_in, const int* in_sizes, int n_in,
                              void* d_out, int out_size, void* d_ws, size_t ws_size,
                              hipStream_t stream) {
    const float* X     = (const float*)d_in[0];   // [2,2048,1024]
    const float* Wqkv  = (const float*)d_in[1];   // [1024,3072]
    const float* bqkv  = (const float*)d_in[2];   // [3072]
    const float* Wproj = (const float*)d_in[3];   // [1024,1024]
    const float* bproj = (const float*)d_in[4];   // [1024]
    float* Out = (float*)d_out;                   // [2,2048,1024] fp32

    // workspace layout (bf16 elements), total ~48 MB
    ushort* Xb     = (ushort*)d_ws;
    ushort* WqkvT  = Xb + (size_t)4096 * 1024;
    ushort* WprojT = WqkvT + (size_t)3072 * 1024;
    ushort* Qb     = WprojT + (size_t)1024 * 1024;  // [b,h,s,d] prescaled
    ushort* Kb     = Qb + (size_t)4096 * 1024;      // [b,h,s,d]
    ushort* VT     = Kb + (size_t)4096 * 1024;      // [b,h,d,s]
    ushort* CTX    = VT + (size_t)4096 * 1024;      // [tok, 1024] merged heads

    cast_x_kernel<<<4096, 256, 0, stream>>>(X, Xb);
    transpose_cast_kernel<<<dim3(48, 16), 256, 0, stream>>>(Wqkv, WqkvT, 1024, 3072);
    transpose_cast_kernel<<<dim3(16, 16), 256, 0, stream>>>(Wproj, WprojT, 1024, 1024);
    gemm_bt_kernel<0><<<dim3(24, 32), 256, 0, stream>>>(Xb, WqkvT, bqkv, Qb, Kb, VT, nullptr,
                                                        4096, 3072, 1024);
    attn_kernel<<<2048, 64, 0, stream>>>(Qb, Kb, VT, CTX);
    gemm_bt_kernel<1><<<dim3(8, 32), 256, 0, stream>>>(CTX, WprojT, bproj, nullptr, nullptr,
                                                       nullptr, Out, 4096, 1024, 1024);
}

// Round 7
// 211.670 us; speedup vs baseline: 6.0356x; 6.0356x over previous
//
#include <hip/hip_runtime.h>
#include <hip/hip_bf16.h>

typedef __attribute__((ext_vector_type(8))) short short8;     // 8 bf16 (4 VGPRs) MFMA A/B frag
typedef __attribute__((ext_vector_type(4))) float f32x4;      // 16x16 MFMA C/D frag
typedef __attribute__((ext_vector_type(16))) float f32x16;    // 32x32 MFMA C/D frag
typedef __attribute__((ext_vector_type(4))) unsigned short u16x4;
typedef __attribute__((ext_vector_type(4))) unsigned int u32x4;

#define MFMA16(a, b, c) __builtin_amdgcn_mfma_f32_16x16x32_bf16((a), (b), (c), 0, 0, 0)
#define MFMA32(a, b, c) __builtin_amdgcn_mfma_f32_32x32x16_bf16((a), (b), (c), 0, 0, 0)

__device__ __forceinline__ unsigned short f2bf(float f) {
    union { float f; unsigned u; } v; v.f = f;
    return (unsigned short)((v.u + 0x7fffu + ((v.u >> 16) & 1u)) >> 16);
}

// ---------------------------------------------------------------- cast X -> bf16
__global__ void cast_x_kernel(const float* __restrict__ x, ushort* __restrict__ y) {
    int i = blockIdx.x * blockDim.x + threadIdx.x;      // one float4 per thread, exact grid
    float4 v = ((const float4*)x)[i];
    u16x4 o = { f2bf(v.x), f2bf(v.y), f2bf(v.z), f2bf(v.w) };
    *(u16x4*)(y + (size_t)i * 4) = o;
}

// ------------------------------------------- W [K][N] f32 -> WT [N][K] bf16
__global__ void transpose_cast_kernel(const float* __restrict__ W, ushort* __restrict__ WT,
                                      int K, int N) {
    __shared__ ushort t[64][66];                        // 66: odd word stride, conflict-free
    int n0 = blockIdx.x * 64, k0 = blockIdx.y * 64;
    int tn = threadIdx.x & 63, tg = threadIdx.x >> 6;
#pragma unroll
    for (int i = 0; i < 16; ++i) {
        int k = tg * 16 + i;
        t[tn][k] = f2bf(W[(size_t)(k0 + k) * N + n0 + tn]);
    }
    __syncthreads();
#pragma unroll
    for (int i = 0; i < 16; ++i) {
        int nn = tg * 16 + i;
        WT[(size_t)(n0 + nn) * K + k0 + tn] = t[nn][tn];
    }
}

// ---------------------------------------------------------------- GEMM C = A @ BT^T
// A [M][K] bf16 row-major, BT [N][K] bf16 (n-major). 128x128 tile, BK=64, 4 waves.
// MODE 0: QKV epilogue -> scatter Q (prescaled), K, VT (transposed V), bf16.
// MODE 1: proj epilogue -> Out fp32 [M][N].
#define QSCALE 0.18033688011112042f   /* 0.125 * log2(e) */

template <int MODE>
__global__ __launch_bounds__(256)
void gemm_bt_kernel(const ushort* __restrict__ A, const ushort* __restrict__ BT,
                    const float* __restrict__ bias,
                    ushort* __restrict__ Qb, ushort* __restrict__ Kb,
                    ushort* __restrict__ VT, float* __restrict__ Out,
                    int M, int N, int K) {
    __shared__ ushort Asm[128 * 64];
    __shared__ ushort Bsm[128 * 64];
    const int lane = threadIdx.x & 63;
    const int wv = threadIdx.x >> 6;
    const int l15 = lane & 15, lg = lane >> 4;
    const int rm = (wv >> 1) * 64, cn = (wv & 1) * 64;  // wave's 64x64 sub-tile
    const int row0 = blockIdx.y * 128, col0 = blockIdx.x * 128;

    const char* Agb = (const char*)(A + (size_t)row0 * K);
    const char* Bgb = (const char*)(BT + (size_t)col0 * K);
    const size_t rowbytes = (size_t)K * 2;

    f32x4 acc[4][4];
#pragma unroll
    for (int mi = 0; mi < 4; ++mi)
#pragma unroll
        for (int ni = 0; ni < 4; ++ni) acc[mi][ni] = f32x4{0.f, 0.f, 0.f, 0.f};

    const int grow_l = (lane >> 3);          // 0..7 within 8-row chunk
    const int gcol_l = (lane & 7) * 16;      // byte within 128B row

    for (int k0 = 0; k0 < K; k0 += 64) {
#pragma unroll
        for (int c = 0; c < 4; ++c) {
            int chunk = wv * 4 + c;                       // 16 chunks of 1KB
            size_t go = (size_t)(chunk * 8 + grow_l) * rowbytes + (size_t)k0 * 2 + gcol_l;
            int lo = chunk * 1024 + lane * 16;
            __builtin_amdgcn_global_load_lds(
                (const __attribute__((address_space(1))) void*)(Agb + go),
                (__attribute__((address_space(3))) void*)((char*)Asm + lo), 16, 0, 0);
            __builtin_amdgcn_global_load_lds(
                (const __attribute__((address_space(1))) void*)(Bgb + go),
                (__attribute__((address_space(3))) void*)((char*)Bsm + lo), 16, 0, 0);
        }
        __syncthreads();
#pragma unroll
        for (int ks = 0; ks < 2; ++ks) {
            short8 af[4], bf[4];
#pragma unroll
            for (int mi = 0; mi < 4; ++mi)
                af[mi] = *(const short8*)&Asm[(rm + mi * 16 + l15) * 64 + ks * 32 + lg * 8];
#pragma unroll
            for (int ni = 0; ni < 4; ++ni)
                bf[ni] = *(const short8*)&Bsm[(cn + ni * 16 + l15) * 64 + ks * 32 + lg * 8];
#pragma unroll
            for (int mi = 0; mi < 4; ++mi)
#pragma unroll
                for (int ni = 0; ni < 4; ++ni)
                    acc[mi][ni] = MFMA16(af[mi], bf[ni], acc[mi][ni]);
        }
        __syncthreads();
    }

    // Epilogue. D layout: lane holds D[(lg)*4+j][l15] (row=M dim, col=N dim).
    if (MODE == 0) {
        const int sect = col0 >> 10;   // 0=q 1=k 2=v, uniform per block (128 | 1024)
#pragma unroll
        for (int ni = 0; ni < 4; ++ni) {
            int col = col0 + cn + ni * 16 + l15;
            float bv = bias[col];
            int dcol = col & 1023, h = dcol >> 6, dd = dcol & 63;
#pragma unroll
            for (int mi = 0; mi < 4; ++mi) {
                int mrow0 = row0 + rm + mi * 16 + lg * 4;
                if (sect == 2) {
                    int b = mrow0 >> 11, s = mrow0 & 2047;   // 4 consecutive s, same b
                    u16x4 o;
#pragma unroll
                    for (int j = 0; j < 4; ++j) o[j] = f2bf(acc[mi][ni][j] + bv);
                    *(u16x4*)&VT[((size_t)((b << 4) + h) * 64 + dd) * 2048 + s] = o;
                } else {
                    ushort* dst = sect ? Kb : Qb;
                    float sc = sect ? 1.f : QSCALE;
#pragma unroll
                    for (int j = 0; j < 4; ++j) {
                        int tok = mrow0 + j;
                        int b = tok >> 11, s = tok & 2047;
                        dst[((size_t)((b << 4) + h) * 2048 + s) * 64 + dd] =
                            f2bf((acc[mi][ni][j] + bv) * sc);
                    }
                }
            }
        }
    } else {
#pragma unroll
        for (int ni = 0; ni < 4; ++ni) {
            int col = col0 + cn + ni * 16 + l15;
            float bv = bias[col];
#pragma unroll
            for (int mi = 0; mi < 4; ++mi) {
                int mrow0 = row0 + rm + mi * 16 + lg * 4;
#pragma unroll
                for (int j = 0; j < 4; ++j)
                    Out[(size_t)(mrow0 + j) * N + col] = acc[mi][ni][j] + bv;
            }
        }
    }
}

// ---------------------------------------------------------------- causal flash attention v5
// 1 wave/block, no LDS, no barriers, NO INLINE ASM. K/V per head (512KB) is
// L2-resident (4 heads pinned per XCD); fragments read directly from global.
// All fragment arrays statically indexed (rule #20). Uniform loop body: both
// 32-key half-tiles always computed; causal mask applied to both on the last
// chunk (fully-masked upper half contributes exact zeros). P re-fragmentation
// via f2bf pack + __shfl_xor(.,32) — builtin cross-lane, no tied-operand asm.
// Defer-max THR=8 (T13). setprio around MFMA clusters (T5).
// Grid: 2048 blocks = 8 xcd x (4 heads x 64 tiles); tile order 63,0,62,1,...
// so any 8 consecutive blocks pair heavy+light (each pair = 33 chunks).
__global__ __launch_bounds__(64, 2)
void attn_kernel(const ushort* __restrict__ Qb, const ushort* __restrict__ Kb,
                 const ushort* __restrict__ VT, ushort* __restrict__ CTX) {
    const int lane = threadIdx.x;                        // 0..63
    const int l31 = lane & 31;
    const int hi = lane >> 5;                            // 0/1
    const int id = blockIdx.x;
    const int xcd = id & 7, jj = id >> 3;                // jj 0..255
    const int bh = (xcd << 2) + (jj >> 6);               // 4 heads per XCD
    const int s = jj & 63;
    const int t = (s & 1) ? (s >> 1) : 63 - (s >> 1);    // interleaved LPT
    const int q0 = t * 32;
    const int qrow = q0 + l31;

    const ushort* Qh = Qb + (size_t)bh * 2048 * 64;
    const ushort* Kh = Kb + (size_t)bh * 2048 * 64;
    const ushort* Vh = VT + (size_t)bh * 64 * 2048;

    // Q fragments (B-operand of mfma(K,Q)): Q[qrow][dc*16 + hi*8 .. +7]
    short8 qf[4];
#pragma unroll
    for (int dc = 0; dc < 4; ++dc)
        qf[dc] = *(const short8*)&Qh[(size_t)qrow * 64 + dc * 16 + hi * 8];

    const int nc = (t >> 1) + 1;                         // 64-key chunks

    float mrun = -1e30f, lsum = 0.f;
    f32x16 acc0, acc1;                                   // ctx^T d 0..31 / 32..63
#pragma unroll
    for (int r = 0; r < 16; ++r) { acc0[r] = 0.f; acc1[r] = 0.f; }

    for (int c = 0; c < nc; ++c) {
        const int kb = c * 64;

        // ---- K fragments (A-operand): K[kb + {0,32} + l31][dc*16 + hi*8]
        // All in-bounds: kb+63 <= 2047 for every tile's chunk range.
        const ushort* kbase = Kh + (size_t)(kb + l31) * 64 + hi * 8;
        short8 kf0[4], kf1[4];
#pragma unroll
        for (int dc = 0; dc < 4; ++dc) {
            kf0[dc] = *(const short8*)(kbase + dc * 16);
            kf1[dc] = *(const short8*)(kbase + 2048 + dc * 16);
        }
        // ---- V fragments (A-operand of PV): VT[{0,32}+l31][kb + j*16 + hi*8]
        const ushort* vbase = Vh + (size_t)l31 * 2048 + kb + hi * 8;
        short8 vf0[4], vf1[4];
#pragma unroll
        for (int j = 0; j < 4; ++j) {
            vf0[j] = *(const short8*)(vbase + j * 16);
            vf1[j] = *(const short8*)(vbase + 32 * 2048 + j * 16);
        }

        // ---- QK^T: two 32x32 S-tiles
        f32x16 st0, st1;
#pragma unroll
        for (int r = 0; r < 16; ++r) { st0[r] = 0.f; st1[r] = 0.f; }
        __builtin_amdgcn_s_setprio(1);
#pragma unroll
        for (int dc = 0; dc < 4; ++dc) st0 = MFMA32(kf0[dc], qf[dc], st0);
#pragma unroll
        for (int dc = 0; dc < 4; ++dc) st1 = MFMA32(kf1[dc], qf[dc], st1);
        __builtin_amdgcn_s_setprio(0);

        // ---- causal mask, both tiles, last chunk only.
        // C/D layout: reg r of lane -> key_local = (r&3) + 8*(r>>2) + 4*hi.
        if (c == nc - 1) {
            const int base0 = kb + (hi << 2);
#pragma unroll
            for (int r = 0; r < 16; ++r) {
                int k = base0 + ((r & 3) + 8 * (r >> 2));
                st0[r] = (k <= qrow) ? st0[r] : -1e30f;
                st1[r] = (k + 32 <= qrow) ? st1[r] : -1e30f;
            }
        }

        // ---- online softmax (log2 domain), defer-max THR=8
        float tmax = st0[0];
#pragma unroll
        for (int r = 1; r < 16; ++r) tmax = fmaxf(tmax, st0[r]);
#pragma unroll
        for (int r = 0; r < 16; ++r) tmax = fmaxf(tmax, st1[r]);
        tmax = fmaxf(tmax, __shfl_xor(tmax, 32));        // partner holds other key-half

        if (!__all(tmax <= mrun + 8.0f)) {
            float mnew = fmaxf(mrun, tmax);
            float sc = exp2f(mrun - mnew);
#pragma unroll
            for (int r = 0; r < 16; ++r) { acc0[r] *= sc; acc1[r] *= sc; }
            lsum *= sc;
            mrun = mnew;
        }

        float tsum = 0.f;
#pragma unroll
        for (int r = 0; r < 16; ++r) { st0[r] = exp2f(st0[r] - mrun); tsum += st0[r]; }
#pragma unroll
        for (int r = 0; r < 16; ++r) { st1[r] = exp2f(st1[r] - mrun); tsum += st1[r]; }
        lsum += tsum;                                    // partner partial merged at end

        // ---- P re-frag in registers + PV.
        // Lane owns keys {4hi+0..3, 8+4hi+0..3, ...}; B-frag for a 16-key group
        // needs keys hi*8..hi*8+7 -> exchange two packed words with lane^32.
#define PACK2(a, b) (((unsigned)f2bf(a)) | (((unsigned)f2bf(b)) << 16))
#define MAKE_PFRAG(st, kcL, out)                                                        \
    do {                                                                                \
        unsigned w0 = PACK2(st[8 * kcL + 0], st[8 * kcL + 1]);                          \
        unsigned w1 = PACK2(st[8 * kcL + 2], st[8 * kcL + 3]);                          \
        unsigned w2 = PACK2(st[8 * kcL + 4], st[8 * kcL + 5]);                          \
        unsigned w3 = PACK2(st[8 * kcL + 6], st[8 * kcL + 7]);                          \
        unsigned e0 = hi ? w0 : w2, e1 = hi ? w1 : w3;                                  \
        unsigned r0 = __shfl_xor(e0, 32);                                               \
        unsigned r1 = __shfl_xor(e1, 32);                                               \
        u32x4 fw;                                                                       \
        fw.x = hi ? r0 : w0;                                                            \
        fw.y = hi ? r1 : w1;                                                            \
        fw.z = hi ? w2 : r0;                                                            \
        fw.w = hi ? w3 : r1;                                                            \
        out = __builtin_bit_cast(short8, fw);                                           \
    } while (0)

        short8 pf;
        MAKE_PFRAG(st0, 0, pf);
        __builtin_amdgcn_s_setprio(1);
        acc0 = MFMA32(vf0[0], pf, acc0);
        acc1 = MFMA32(vf1[0], pf, acc1);
        __builtin_amdgcn_s_setprio(0);
        MAKE_PFRAG(st0, 1, pf);
        __builtin_amdgcn_s_setprio(1);
        acc0 = MFMA32(vf0[1], pf, acc0);
        acc1 = MFMA32(vf1[1], pf, acc1);
        __builtin_amdgcn_s_setprio(0);
        MAKE_PFRAG(st1, 0, pf);
        __builtin_amdgcn_s_setprio(1);
        acc0 = MFMA32(vf0[2], pf, acc0);
        acc1 = MFMA32(vf1[2], pf, acc1);
        __builtin_amdgcn_s_setprio(0);
        MAKE_PFRAG(st1, 1, pf);
        __builtin_amdgcn_s_setprio(1);
        acc0 = MFMA32(vf0[3], pf, acc0);
        acc1 = MFMA32(vf1[3], pf, acc1);
        __builtin_amdgcn_s_setprio(0);
#undef MAKE_PFRAG
#undef PACK2
    }

    lsum += __shfl_xor(lsum, 32);                        // merge partner halves
    const float inv = 1.f / lsum;
    const int b = bh >> 4, h = bh & 15;
    const size_t tokrow = ((size_t)b * 2048 + q0 + l31) * 1024 + (size_t)h * 64;

#define WRITE_DT(accv, dt)                                                              \
    do {                                                                                \
        _Pragma("unroll")                                                               \
        for (int q2 = 0; q2 < 4; ++q2) {                                                \
            int d0 = dt * 32 + 8 * q2 + (hi << 2);                                      \
            u16x4 o;                                                                    \
            _Pragma("unroll")                                                           \
            for (int j = 0; j < 4; ++j) o[j] = f2bf(accv[4 * q2 + j] * inv);            \
            *(u16x4*)&CTX[tokrow + d0] = o;                                             \
        }                                                                               \
    } while (0)

    WRITE_DT(acc0, 0);
    WRITE_DT(acc1, 1);
#undef WRITE_DT
}

// ----------------------------------------------------------------------------
extern "C" void kernel_launch(void* const* d_in, const int* in_sizes, int n_in,
                              void* d_out, int out_size, void* d_ws, size_t ws_size,
                              hipStream_t stream) {
    const float* X     = (const float*)d_in[0];   // [2,2048,1024]
    const float* Wqkv  = (const float*)d_in[1];   // [1024,3072]
    const float* bqkv  = (const float*)d_in[2];   // [3072]
    const float* Wproj = (const float*)d_in[3];   // [1024,1024]
    const float* bproj = (const float*)d_in[4];   // [1024]
    float* Out = (float*)d_out;                   // [2,2048,1024] fp32

    // workspace layout (bf16 elements), total ~48 MB
    ushort* Xb     = (ushort*)d_ws;
    ushort* WqkvT  = Xb + (size_t)4096 * 1024;
    ushort* WprojT = WqkvT + (size_t)3072 * 1024;
    ushort* Qb     = WprojT + (size_t)1024 * 1024;  // [b,h,s,d] prescaled
    ushort* Kb     = Qb + (size_t)4096 * 1024;      // [b,h,s,d]
    ushort* VT     = Kb + (size_t)4096 * 1024;      // [b,h,d,s]
    ushort* CTX    = VT + (size_t)4096 * 1024;      // [tok, 1024] merged heads

    cast_x_kernel<<<4096, 256, 0, stream>>>(X, Xb);
    transpose_cast_kernel<<<dim3(48, 16), 256, 0, stream>>>(Wqkv, WqkvT, 1024, 3072);
    transpose_cast_kernel<<<dim3(16, 16), 256, 0, stream>>>(Wproj, WprojT, 1024, 1024);
    gemm_bt_kernel<0><<<dim3(24, 32), 256, 0, stream>>>(Xb, WqkvT, bqkv, Qb, Kb, VT, nullptr,
                                                        4096, 3072, 1024);
    attn_kernel<<<2048, 64, 0, stream>>>(Qb, Kb, VT, CTX);
    gemm_bt_kernel<1><<<dim3(8, 32), 256, 0, stream>>>(CTX, WprojT, bproj, nullptr, nullptr,
                                                       nullptr, Out, 4096, 1024, 1024);
}

// Round 8
// 195.034 us; speedup vs baseline: 6.5504x; 1.0853x over previous
//
#include <hip/hip_runtime.h>
#include <hip/hip_bf16.h>

typedef __attribute__((ext_vector_type(8))) short short8;     // 8 bf16 (4 VGPRs) MFMA A/B frag
typedef __attribute__((ext_vector_type(4))) float f32x4;      // 16x16 MFMA C/D frag
typedef __attribute__((ext_vector_type(16))) float f32x16;    // 32x32 MFMA C/D frag
typedef __attribute__((ext_vector_type(4))) unsigned short u16x4;
typedef __attribute__((ext_vector_type(4))) unsigned int u32x4;

#define MFMA16(a, b, c) __builtin_amdgcn_mfma_f32_16x16x32_bf16((a), (b), (c), 0, 0, 0)
#define MFMA32(a, b, c) __builtin_amdgcn_mfma_f32_32x32x16_bf16((a), (b), (c), 0, 0, 0)

__device__ __forceinline__ unsigned short f2bf(float f) {
    union { float f; unsigned u; } v; v.f = f;
    return (unsigned short)((v.u + 0x7fffu + ((v.u >> 16) & 1u)) >> 16);
}

// ---------------------------------------------------------------- cast X -> bf16
__global__ void cast_x_kernel(const float* __restrict__ x, ushort* __restrict__ y) {
    int i = blockIdx.x * blockDim.x + threadIdx.x;      // one float4 per thread, exact grid
    float4 v = ((const float4*)x)[i];
    u16x4 o = { f2bf(v.x), f2bf(v.y), f2bf(v.z), f2bf(v.w) };
    *(u16x4*)(y + (size_t)i * 4) = o;
}

// ------------------------------------------- W [K][N] f32 -> WT [N][K] bf16
__global__ void transpose_cast_kernel(const float* __restrict__ W, ushort* __restrict__ WT,
                                      int K, int N) {
    __shared__ ushort t[64][66];                        // 66: odd word stride, conflict-free
    int n0 = blockIdx.x * 64, k0 = blockIdx.y * 64;
    int tn = threadIdx.x & 63, tg = threadIdx.x >> 6;
#pragma unroll
    for (int i = 0; i < 16; ++i) {
        int k = tg * 16 + i;
        t[tn][k] = f2bf(W[(size_t)(k0 + k) * N + n0 + tn]);
    }
    __syncthreads();
#pragma unroll
    for (int i = 0; i < 16; ++i) {
        int nn = tg * 16 + i;
        WT[(size_t)(n0 + nn) * K + k0 + tn] = t[nn][tn];
    }
}

// ---------------------------------------------------------------- GEMM C = A @ BT^T
// A [M][K] bf16 row-major, BT [N][K] bf16 (n-major). 128x128 tile, BK=64, 4 waves.
// MODE 0: QKV epilogue -> scatter Q (prescaled), K, VT (transposed V), bf16.
// MODE 1: proj epilogue -> Out fp32 [M][N].
#define QSCALE 0.18033688011112042f   /* 0.125 * log2(e) */

template <int MODE>
__global__ __launch_bounds__(256)
void gemm_bt_kernel(const ushort* __restrict__ A, const ushort* __restrict__ BT,
                    const float* __restrict__ bias,
                    ushort* __restrict__ Qb, ushort* __restrict__ Kb,
                    ushort* __restrict__ VT, float* __restrict__ Out,
                    int M, int N, int K) {
    __shared__ ushort Asm[128 * 64];
    __shared__ ushort Bsm[128 * 64];
    const int lane = threadIdx.x & 63;
    const int wv = threadIdx.x >> 6;
    const int l15 = lane & 15, lg = lane >> 4;
    const int rm = (wv >> 1) * 64, cn = (wv & 1) * 64;  // wave's 64x64 sub-tile
    const int row0 = blockIdx.y * 128, col0 = blockIdx.x * 128;

    const char* Agb = (const char*)(A + (size_t)row0 * K);
    const char* Bgb = (const char*)(BT + (size_t)col0 * K);
    const size_t rowbytes = (size_t)K * 2;

    f32x4 acc[4][4];
#pragma unroll
    for (int mi = 0; mi < 4; ++mi)
#pragma unroll
        for (int ni = 0; ni < 4; ++ni) acc[mi][ni] = f32x4{0.f, 0.f, 0.f, 0.f};

    const int grow_l = (lane >> 3);          // 0..7 within 8-row chunk
    const int gcol_l = (lane & 7) * 16;      // byte within 128B row

    for (int k0 = 0; k0 < K; k0 += 64) {
#pragma unroll
        for (int c = 0; c < 4; ++c) {
            int chunk = wv * 4 + c;                       // 16 chunks of 1KB
            size_t go = (size_t)(chunk * 8 + grow_l) * rowbytes + (size_t)k0 * 2 + gcol_l;
            int lo = chunk * 1024 + lane * 16;
            __builtin_amdgcn_global_load_lds(
                (const __attribute__((address_space(1))) void*)(Agb + go),
                (__attribute__((address_space(3))) void*)((char*)Asm + lo), 16, 0, 0);
            __builtin_amdgcn_global_load_lds(
                (const __attribute__((address_space(1))) void*)(Bgb + go),
                (__attribute__((address_space(3))) void*)((char*)Bsm + lo), 16, 0, 0);
        }
        __syncthreads();
#pragma unroll
        for (int ks = 0; ks < 2; ++ks) {
            short8 af[4], bf[4];
#pragma unroll
            for (int mi = 0; mi < 4; ++mi)
                af[mi] = *(const short8*)&Asm[(rm + mi * 16 + l15) * 64 + ks * 32 + lg * 8];
#pragma unroll
            for (int ni = 0; ni < 4; ++ni)
                bf[ni] = *(const short8*)&Bsm[(cn + ni * 16 + l15) * 64 + ks * 32 + lg * 8];
#pragma unroll
            for (int mi = 0; mi < 4; ++mi)
#pragma unroll
                for (int ni = 0; ni < 4; ++ni)
                    acc[mi][ni] = MFMA16(af[mi], bf[ni], acc[mi][ni]);
        }
        __syncthreads();
    }

    // Epilogue. D layout: lane holds D[(lg)*4+j][l15] (row=M dim, col=N dim).
    if (MODE == 0) {
        const int sect = col0 >> 10;   // 0=q 1=k 2=v, uniform per block (128 | 1024)
#pragma unroll
        for (int ni = 0; ni < 4; ++ni) {
            int col = col0 + cn + ni * 16 + l15;
            float bv = bias[col];
            int dcol = col & 1023, h = dcol >> 6, dd = dcol & 63;
#pragma unroll
            for (int mi = 0; mi < 4; ++mi) {
                int mrow0 = row0 + rm + mi * 16 + lg * 4;
                if (sect == 2) {
                    int b = mrow0 >> 11, s = mrow0 & 2047;   // 4 consecutive s, same b
                    u16x4 o;
#pragma unroll
                    for (int j = 0; j < 4; ++j) o[j] = f2bf(acc[mi][ni][j] + bv);
                    *(u16x4*)&VT[((size_t)((b << 4) + h) * 64 + dd) * 2048 + s] = o;
                } else {
                    ushort* dst = sect ? Kb : Qb;
                    float sc = sect ? 1.f : QSCALE;
#pragma unroll
                    for (int j = 0; j < 4; ++j) {
                        int tok = mrow0 + j;
                        int b = tok >> 11, s = tok & 2047;
                        dst[((size_t)((b << 4) + h) * 2048 + s) * 64 + dd] =
                            f2bf((acc[mi][ni][j] + bv) * sc);
                    }
                }
            }
        }
    } else {
#pragma unroll
        for (int ni = 0; ni < 4; ++ni) {
            int col = col0 + cn + ni * 16 + l15;
            float bv = bias[col];
#pragma unroll
            for (int mi = 0; mi < 4; ++mi) {
                int mrow0 = row0 + rm + mi * 16 + lg * 4;
#pragma unroll
                for (int j = 0; j < 4; ++j)
                    Out[(size_t)(mrow0 + j) * N + col] = acc[mi][ni][j] + bv;
            }
        }
    }
}

// ---------------------------------------------------------------- causal flash attention v6
// v3b structure (LDS-staged, 78.6us) with concurrency fixes:
//  - 2 waves/block (64 q-rows), 1024 blocks = 4 blocks/CU (was 2) -> 4 independent
//    chunk pipelines per CU overlap each other's stage/barrier stalls.
//  - interleaved pair-LPT tile order (31,0,30,1,...): adjacent blocks sum to
//    equal work (t+1 chunks, pairs = 33).
//  - barriers couple only 2 waves.
// Retained (all previously verified): K/V double-buffered LDS via global_load_lds
// with XOR-swizzled source + swizzled reads (rule #21); swapped QK^T 32x32 MFMA;
// in-register P re-frag via f2bf pack + __shfl_xor (asm-free, v5); uniform
// diagonal mask on both half-tiles; defer-max THR=8; setprio around MFMA.
__global__ __launch_bounds__(128, 2)
void attn_kernel(const ushort* __restrict__ Qb, const ushort* __restrict__ Kb,
                 const ushort* __restrict__ VT, ushort* __restrict__ CTX) {
    __shared__ __align__(16) ushort Ksm[2][64 * 64];    // [key][d], 16B-unit XOR-swizzled
    __shared__ __align__(16) ushort Vsm[2][64 * 64];    // [d][key], 16B-unit XOR-swizzled

    const int tid = threadIdx.x;                         // 0..127
    const int lane = tid & 63;
    const int w = tid >> 6;                              // wave 0/1
    const int l31 = lane & 31;
    const int hi = lane >> 5;                            // 0/1
    const int r7 = l31 & 7;

    // block remap: 1024 blocks = 8 xcd x (4 heads x 32 tiles); interleaved LPT.
    const int id = blockIdx.x;
    const int xcd = id & 7, jj = id >> 3;                // jj 0..127
    const int bh = (xcd << 2) + (jj >> 5);               // 4 heads per XCD (L2-resident K/V)
    const int s = jj & 31;
    const int t = (s & 1) ? (s >> 1) : 31 - (s >> 1);    // pairs (31,0),(30,1),... sum 33
    const int q0 = t * 64 + w * 32;                      // wave's 32 q-rows
    const int qrow = q0 + l31;

    const ushort* Qh = Qb + (size_t)bh * 2048 * 64;
    const ushort* Kh = Kb + (size_t)bh * 2048 * 64;
    const ushort* Vh = VT + (size_t)bh * 64 * 2048;

    // Q fragments (B-operand of mfma(K,Q)): Q[qrow][dc*16 + hi*8 .. +7]
    short8 qf[4];
#pragma unroll
    for (int dc = 0; dc < 4; ++dc)
        qf[dc] = *(const short8*)&Qh[(size_t)qrow * 64 + dc * 16 + hi * 8];

    // staging geometry: 128 threads x 4 slots x 16B per tile (64 rows x 8 slots).
    // slot_id = tid + i*128 -> row = srow + 16*i, col = scol (same all i).
    const int srow = tid >> 3, scol = tid & 7;
    const int swcol = (scol ^ (srow & 7)) * 8;           // pre-swizzled source col (elems)

#define GLL(src, dst) __builtin_amdgcn_global_load_lds(                                 \
        (const __attribute__((address_space(1))) void*)(src),                           \
        (__attribute__((address_space(3))) void*)(dst), 16, 0, 0)

#define STAGE(buf, kb_)                                                                 \
    do {                                                                                \
        _Pragma("unroll")                                                               \
        for (int i_ = 0; i_ < 4; ++i_) {                                                \
            const int row_ = srow + 16 * i_;                                            \
            GLL(Kh + (size_t)((kb_) + row_) * 64 + swcol,                               \
                (char*)&Ksm[buf][0] + (tid + i_ * 128) * 16);                           \
            GLL(Vh + (size_t)row_ * 2048 + (kb_) + swcol,                               \
                (char*)&Vsm[buf][0] + (tid + i_ * 128) * 16);                           \
        }                                                                               \
    } while (0)

    const int nc = t + 1;                                // 64-key chunks for this block

    STAGE(0, 0);
    __syncthreads();

    float mrun = -1e30f, lsum = 0.f;
    f32x16 acc0, acc1;                                   // ctx^T d 0..31 / 32..63
#pragma unroll
    for (int r = 0; r < 16; ++r) { acc0[r] = 0.f; acc1[r] = 0.f; }

    int cur = 0;
    for (int c = 0; c < nc; ++c) {
        const int kb = c * 64;
        if (c + 1 < nc) STAGE(cur ^ 1, kb + 64);

        const ushort* Kc = &Ksm[cur][0];
        const ushort* Vc = &Vsm[cur][0];

        // ---- QK^T: two 32x32 S-tiles (keys kb..+31, kb+32..+63)
        f32x16 st0, st1;
#pragma unroll
        for (int r = 0; r < 16; ++r) { st0[r] = 0.f; st1[r] = 0.f; }
        __builtin_amdgcn_s_setprio(1);
#pragma unroll
        for (int dc = 0; dc < 4; ++dc) {
            short8 kf0 = *(const short8*)(Kc + l31 * 64 + (((dc * 2 + hi) ^ r7) << 3));
            short8 kf1 = *(const short8*)(Kc + (32 + l31) * 64 + (((dc * 2 + hi) ^ r7) << 3));
            st0 = MFMA32(kf0, qf[dc], st0);
            st1 = MFMA32(kf1, qf[dc], st1);
        }
        __builtin_amdgcn_s_setprio(0);

        // ---- causal mask, both tiles, last chunk only (uniform; wave1's st0 unaffected).
        // C/D layout: reg r -> key_local = (r&3) + 8*(r>>2) + 4*hi.
        if (c == nc - 1) {
            const int base0 = kb + (hi << 2);
#pragma unroll
            for (int r = 0; r < 16; ++r) {
                int k = base0 + ((r & 3) + 8 * (r >> 2));
                st0[r] = (k <= qrow) ? st0[r] : -1e30f;
                st1[r] = (k + 32 <= qrow) ? st1[r] : -1e30f;
            }
        }

        // ---- online softmax (log2 domain), defer-max THR=8
        float tmax = st0[0];
#pragma unroll
        for (int r = 1; r < 16; ++r) tmax = fmaxf(tmax, st0[r]);
#pragma unroll
        for (int r = 0; r < 16; ++r) tmax = fmaxf(tmax, st1[r]);
        tmax = fmaxf(tmax, __shfl_xor(tmax, 32));        // partner holds other key-half

        if (!__all(tmax <= mrun + 8.0f)) {
            float mnew = fmaxf(mrun, tmax);
            float sc = exp2f(mrun - mnew);
#pragma unroll
            for (int r = 0; r < 16; ++r) { acc0[r] *= sc; acc1[r] *= sc; }
            lsum *= sc;
            mrun = mnew;
        }

        float tsum = 0.f;
#pragma unroll
        for (int r = 0; r < 16; ++r) { st0[r] = exp2f(st0[r] - mrun); tsum += st0[r]; }
#pragma unroll
        for (int r = 0; r < 16; ++r) { st1[r] = exp2f(st1[r] - mrun); tsum += st1[r]; }
        lsum += tsum;                                    // partner partial merged at end

        // ---- P re-frag in registers + PV (f2bf pack + shfl_xor; verified v5)
#define PACK2(a, b) (((unsigned)f2bf(a)) | (((unsigned)f2bf(b)) << 16))
#define MAKE_PFRAG(st, kcL, out)                                                        \
    do {                                                                                \
        unsigned w0 = PACK2(st[8 * kcL + 0], st[8 * kcL + 1]);                          \
        unsigned w1 = PACK2(st[8 * kcL + 2], st[8 * kcL + 3]);                          \
        unsigned w2 = PACK2(st[8 * kcL + 4], st[8 * kcL + 5]);                          \
        unsigned w3 = PACK2(st[8 * kcL + 6], st[8 * kcL + 7]);                          \
        unsigned e0 = hi ? w0 : w2, e1 = hi ? w1 : w3;                                  \
        unsigned r0 = __shfl_xor(e0, 32);                                               \
        unsigned r1 = __shfl_xor(e1, 32);                                               \
        u32x4 fw;                                                                       \
        fw.x = hi ? r0 : w0;                                                            \
        fw.y = hi ? r1 : w1;                                                            \
        fw.z = hi ? w2 : r0;                                                            \
        fw.w = hi ? w3 : r1;                                                            \
        out = __builtin_bit_cast(short8, fw);                                           \
    } while (0)

        short8 pf;
        MAKE_PFRAG(st0, 0, pf);
        __builtin_amdgcn_s_setprio(1);
        {
            short8 v0 = *(const short8*)(Vc + l31 * 64 + ((hi ^ r7) << 3));
            short8 v1 = *(const short8*)(Vc + (32 + l31) * 64 + ((hi ^ r7) << 3));
            acc0 = MFMA32(v0, pf, acc0);
            acc1 = MFMA32(v1, pf, acc1);
        }
        __builtin_amdgcn_s_setprio(0);
        MAKE_PFRAG(st0, 1, pf);
        __builtin_amdgcn_s_setprio(1);
        {
            short8 v0 = *(const short8*)(Vc + l31 * 64 + (((2 + hi) ^ r7) << 3));
            short8 v1 = *(const short8*)(Vc + (32 + l31) * 64 + (((2 + hi) ^ r7) << 3));
            acc0 = MFMA32(v0, pf, acc0);
            acc1 = MFMA32(v1, pf, acc1);
        }
        __builtin_amdgcn_s_setprio(0);
        MAKE_PFRAG(st1, 0, pf);
        __builtin_amdgcn_s_setprio(1);
        {
            short8 v0 = *(const short8*)(Vc + l31 * 64 + (((4 + hi) ^ r7) << 3));
            short8 v1 = *(const short8*)(Vc + (32 + l31) * 64 + (((4 + hi) ^ r7) << 3));
            acc0 = MFMA32(v0, pf, acc0);
            acc1 = MFMA32(v1, pf, acc1);
        }
        __builtin_amdgcn_s_setprio(0);
        MAKE_PFRAG(st1, 1, pf);
        __builtin_amdgcn_s_setprio(1);
        {
            short8 v0 = *(const short8*)(Vc + l31 * 64 + (((6 + hi) ^ r7) << 3));
            short8 v1 = *(const short8*)(Vc + (32 + l31) * 64 + (((6 + hi) ^ r7) << 3));
            acc0 = MFMA32(v0, pf, acc0);
            acc1 = MFMA32(v1, pf, acc1);
        }
        __builtin_amdgcn_s_setprio(0);
#undef MAKE_PFRAG
#undef PACK2

        __syncthreads();
        cur ^= 1;
    }
#undef STAGE
#undef GLL

    lsum += __shfl_xor(lsum, 32);                        // merge partner halves
    const float inv = 1.f / lsum;
    const int b = bh >> 4, h = bh & 15;
    const size_t tokrow = ((size_t)b * 2048 + q0 + l31) * 1024 + (size_t)h * 64;

#define WRITE_DT(accv, dt)                                                              \
    do {                                                                                \
        _Pragma("unroll")                                                               \
        for (int q2 = 0; q2 < 4; ++q2) {                                                \
            int d0 = dt * 32 + 8 * q2 + (hi << 2);                                      \
            u16x4 o;                                                                    \
            _Pragma("unroll")                                                           \
            for (int j = 0; j < 4; ++j) o[j] = f2bf(accv[4 * q2 + j] * inv);            \
            *(u16x4*)&CTX[tokrow + d0] = o;                                             \
        }                                                                               \
    } while (0)

    WRITE_DT(acc0, 0);
    WRITE_DT(acc1, 1);
#undef WRITE_DT
}

// ----------------------------------------------------------------------------
extern "C" void kernel_launch(void* const* d_in, const int* in_sizes, int n_in,
                              void* d_out, int out_size, void* d_ws, size_t ws_size,
                              hipStream_t stream) {
    const float* X     = (const float*)d_in[0];   // [2,2048,1024]
    const float* Wqkv  = (const float*)d_in[1];   // [1024,3072]
    const float* bqkv  = (const float*)d_in[2];   // [3072]
    const float* Wproj = (const float*)d_in[3];   // [1024,1024]
    const float* bproj = (const float*)d_in[4];   // [1024]
    float* Out = (float*)d_out;                   // [2,2048,1024] fp32

    // workspace layout (bf16 elements), total ~48 MB
    ushort* Xb     = (ushort*)d_ws;
    ushort* WqkvT  = Xb + (size_t)4096 * 1024;
    ushort* WprojT = WqkvT + (size_t)3072 * 1024;
    ushort* Qb     = WprojT + (size_t)1024 * 1024;  // [b,h,s,d] prescaled
    ushort* Kb     = Qb + (size_t)4096 * 1024;      // [b,h,s,d]
    ushort* VT     = Kb + (size_t)4096 * 1024;      // [b,h,d,s]
    ushort* CTX    = VT + (size_t)4096 * 1024;      // [tok, 1024] merged heads

    cast_x_kernel<<<4096, 256, 0, stream>>>(X, Xb);
    transpose_cast_kernel<<<dim3(48, 16), 256, 0, stream>>>(Wqkv, WqkvT, 1024, 3072);
    transpose_cast_kernel<<<dim3(16, 16), 256, 0, stream>>>(Wproj, WprojT, 1024, 1024);
    gemm_bt_kernel<0><<<dim3(24, 32), 256, 0, stream>>>(Xb, WqkvT, bqkv, Qb, Kb, VT, nullptr,
                                                        4096, 3072, 1024);
    attn_kernel<<<1024, 128, 0, stream>>>(Qb, Kb, VT, CTX);
    gemm_bt_kernel<1><<<dim3(8, 32), 256, 0, stream>>>(CTX, WprojT, bproj, nullptr, nullptr,
                                                       nullptr, Out, 4096, 1024, 1024);
}

// Round 9
// 168.488 us; speedup vs baseline: 7.5824x; 1.1576x over previous
//
#include <hip/hip_runtime.h>
#include <hip/hip_bf16.h>

typedef __attribute__((ext_vector_type(8))) short short8;     // 8 bf16 (4 VGPRs) MFMA A/B frag
typedef __attribute__((ext_vector_type(4))) float f32x4;      // 16x16 MFMA C/D frag
typedef __attribute__((ext_vector_type(16))) float f32x16;    // 32x32 MFMA C/D frag
typedef __attribute__((ext_vector_type(4))) unsigned short u16x4;
typedef __attribute__((ext_vector_type(4))) unsigned int u32x4;

#define MFMA16(a, b, c) __builtin_amdgcn_mfma_f32_16x16x32_bf16((a), (b), (c), 0, 0, 0)
#define MFMA32(a, b, c) __builtin_amdgcn_mfma_f32_32x32x16_bf16((a), (b), (c), 0, 0, 0)

__device__ __forceinline__ unsigned short f2bf(float f) {
    union { float f; unsigned u; } v; v.f = f;
    return (unsigned short)((v.u + 0x7fffu + ((v.u >> 16) & 1u)) >> 16);
}

__device__ __forceinline__ unsigned cvtpk(float lo, float hi_) {
    unsigned r;
    asm volatile("v_cvt_pk_bf16_f32 %0, %1, %2" : "=v"(r) : "v"(lo), "v"(hi_));
    return r;
}

// ---------------------------------------------------------------- cast X -> bf16
__global__ void cast_x_kernel(const float* __restrict__ x, ushort* __restrict__ y) {
    int i = blockIdx.x * blockDim.x + threadIdx.x;      // one float4 per thread, exact grid
    float4 v = ((const float4*)x)[i];
    u16x4 o = { f2bf(v.x), f2bf(v.y), f2bf(v.z), f2bf(v.w) };
    *(u16x4*)(y + (size_t)i * 4) = o;
}

// ------------------------------------------- W [K][N] f32 -> WT [N][K] bf16
__global__ void transpose_cast_kernel(const float* __restrict__ W, ushort* __restrict__ WT,
                                      int K, int N) {
    __shared__ ushort t[64][66];                        // 66: odd word stride, conflict-free
    int n0 = blockIdx.x * 64, k0 = blockIdx.y * 64;
    int tn = threadIdx.x & 63, tg = threadIdx.x >> 6;
#pragma unroll
    for (int i = 0; i < 16; ++i) {
        int k = tg * 16 + i;
        t[tn][k] = f2bf(W[(size_t)(k0 + k) * N + n0 + tn]);
    }
    __syncthreads();
#pragma unroll
    for (int i = 0; i < 16; ++i) {
        int nn = tg * 16 + i;
        WT[(size_t)(n0 + nn) * K + k0 + tn] = t[nn][tn];
    }
}

// ---------------------------------------------------------------- GEMM C = A @ BT^T
// A [M][K] bf16 row-major, BT [N][K] bf16 (n-major). 128x128 tile, BK=64, 4 waves.
// MODE 0: QKV epilogue -> scatter Q (prescaled), K, VT (transposed V), bf16.
// MODE 1: proj epilogue -> Out fp32 [M][N].
#define QSCALE 0.18033688011112042f   /* 0.125 * log2(e) */

template <int MODE>
__global__ __launch_bounds__(256)
void gemm_bt_kernel(const ushort* __restrict__ A, const ushort* __restrict__ BT,
                    const float* __restrict__ bias,
                    ushort* __restrict__ Qb, ushort* __restrict__ Kb,
                    ushort* __restrict__ VT, float* __restrict__ Out,
                    int M, int N, int K) {
    __shared__ ushort Asm[128 * 64];
    __shared__ ushort Bsm[128 * 64];
    const int lane = threadIdx.x & 63;
    const int wv = threadIdx.x >> 6;
    const int l15 = lane & 15, lg = lane >> 4;
    const int rm = (wv >> 1) * 64, cn = (wv & 1) * 64;  // wave's 64x64 sub-tile
    const int row0 = blockIdx.y * 128, col0 = blockIdx.x * 128;

    const char* Agb = (const char*)(A + (size_t)row0 * K);
    const char* Bgb = (const char*)(BT + (size_t)col0 * K);
    const size_t rowbytes = (size_t)K * 2;

    f32x4 acc[4][4];
#pragma unroll
    for (int mi = 0; mi < 4; ++mi)
#pragma unroll
        for (int ni = 0; ni < 4; ++ni) acc[mi][ni] = f32x4{0.f, 0.f, 0.f, 0.f};

    const int grow_l = (lane >> 3);          // 0..7 within 8-row chunk
    const int gcol_l = (lane & 7) * 16;      // byte within 128B row

    for (int k0 = 0; k0 < K; k0 += 64) {
#pragma unroll
        for (int c = 0; c < 4; ++c) {
            int chunk = wv * 4 + c;                       // 16 chunks of 1KB
            size_t go = (size_t)(chunk * 8 + grow_l) * rowbytes + (size_t)k0 * 2 + gcol_l;
            int lo = chunk * 1024 + lane * 16;
            __builtin_amdgcn_global_load_lds(
                (const __attribute__((address_space(1))) void*)(Agb + go),
                (__attribute__((address_space(3))) void*)((char*)Asm + lo), 16, 0, 0);
            __builtin_amdgcn_global_load_lds(
                (const __attribute__((address_space(1))) void*)(Bgb + go),
                (__attribute__((address_space(3))) void*)((char*)Bsm + lo), 16, 0, 0);
        }
        __syncthreads();
#pragma unroll
        for (int ks = 0; ks < 2; ++ks) {
            short8 af[4], bf[4];
#pragma unroll
            for (int mi = 0; mi < 4; ++mi)
                af[mi] = *(const short8*)&Asm[(rm + mi * 16 + l15) * 64 + ks * 32 + lg * 8];
#pragma unroll
            for (int ni = 0; ni < 4; ++ni)
                bf[ni] = *(const short8*)&Bsm[(cn + ni * 16 + l15) * 64 + ks * 32 + lg * 8];
#pragma unroll
            for (int mi = 0; mi < 4; ++mi)
#pragma unroll
                for (int ni = 0; ni < 4; ++ni)
                    acc[mi][ni] = MFMA16(af[mi], bf[ni], acc[mi][ni]);
        }
        __syncthreads();
    }

    // Epilogue. D layout: lane holds D[(lg)*4+j][l15] (row=M dim, col=N dim).
    if (MODE == 0) {
        const int sect = col0 >> 10;   // 0=q 1=k 2=v, uniform per block (128 | 1024)
#pragma unroll
        for (int ni = 0; ni < 4; ++ni) {
            int col = col0 + cn + ni * 16 + l15;
            float bv = bias[col];
            int dcol = col & 1023, h = dcol >> 6, dd = dcol & 63;
#pragma unroll
            for (int mi = 0; mi < 4; ++mi) {
                int mrow0 = row0 + rm + mi * 16 + lg * 4;
                if (sect == 2) {
                    int b = mrow0 >> 11, s = mrow0 & 2047;   // 4 consecutive s, same b
                    u16x4 o;
#pragma unroll
                    for (int j = 0; j < 4; ++j) o[j] = f2bf(acc[mi][ni][j] + bv);
                    *(u16x4*)&VT[((size_t)((b << 4) + h) * 64 + dd) * 2048 + s] = o;
                } else {
                    ushort* dst = sect ? Kb : Qb;
                    float sc = sect ? 1.f : QSCALE;
#pragma unroll
                    for (int j = 0; j < 4; ++j) {
                        int tok = mrow0 + j;
                        int b = tok >> 11, s = tok & 2047;
                        dst[((size_t)((b << 4) + h) * 2048 + s) * 64 + dd] =
                            f2bf((acc[mi][ni][j] + bv) * sc);
                    }
                }
            }
        }
    } else {
#pragma unroll
        for (int ni = 0; ni < 4; ++ni) {
            int col = col0 + cn + ni * 16 + l15;
            float bv = bias[col];
#pragma unroll
            for (int mi = 0; mi < 4; ++mi) {
                int mrow0 = row0 + rm + mi * 16 + lg * 4;
#pragma unroll
                for (int j = 0; j < 4; ++j)
                    Out[(size_t)(mrow0 + j) * N + col] = acc[mi][ni][j] + bv;
            }
        }
    }
}

// ---------------------------------------------------------------- causal flash attention v7
// = v3b (round 4, 78.6us, verified) + T14 async-STAGE split:
//   staging is now reg-staged: global->VGPR loads for chunk c+1 issued at the TOP
//   of chunk c (before QK), ds_write to the swizzled dest of buf^1 placed BETWEEN
//   softmax and PV (~400cy after issue -> L2 latency hidden under compute).
//   buf^1 was last read in chunk c-1 (barrier since), so mid-chunk writes are safe;
//   still exactly 1 barrier per chunk. LDS layout/content identical to v3b:
//   LDS[row][slot s] = source col (s ^ (row&7)); writes go to slot (scol^(srow&7)).
// Everything else unchanged from v3b: 4 waves x 32 q-rows, 512 blocks heavy-first
// LPT + XCD-pinned (4 heads/XCD), swapped QK^T 32x32, cvt_pk+permlane P re-frag,
// defer-max THR=8, setprio, waves 0/1 skip fully-masked final chunk.
__global__ __launch_bounds__(256)
void attn_kernel(const ushort* __restrict__ Qb, const ushort* __restrict__ Kb,
                 const ushort* __restrict__ VT, ushort* __restrict__ CTX) {
    __shared__ __align__(16) ushort Ksm[2][64 * 64];    // [key][d], 16B-slot XOR-swizzled
    __shared__ __align__(16) ushort Vsm[2][64 * 64];    // [d][key], 16B-slot XOR-swizzled

    const int tid = threadIdx.x;
    const int lane = tid & 63;
    const int w = tid >> 6;
    const int l31 = lane & 31;
    const int hi = lane >> 5;                            // 0/1
    const int r7 = l31 & 7;

    // block remap: 512 blocks = 8 xcd x (4 bh x 16 qt). LPT: heavy (big qt) first.
    const int id = blockIdx.x;
    const int xcd = id & 7, jj = id >> 3;
    const int bh = (xcd << 2) + (jj >> 4);               // 4 heads per XCD -> K/V L2-resident
    const int qt = 15 - (jj & 15);
    const int qw0 = qt * 128 + w * 32;                   // wave's 32 q-rows
    const int qrow = qw0 + l31;

    const ushort* Qh = Qb + (size_t)bh * 2048 * 64;
    const ushort* Kh = Kb + (size_t)bh * 2048 * 64;
    const ushort* Vh = VT + (size_t)bh * 64 * 2048;

    // Q fragments: B-operand of QK mfma: lane needs Q[qrow][dc*16+hi*8..+7]
    short8 qf[4];
#pragma unroll
    for (int dc = 0; dc < 4; ++dc)
        qf[dc] = *(const short8*)&Qh[(size_t)qrow * 64 + dc * 16 + hi * 8];

    // staging geometry: 256 threads, each owns rows {srow, srow+32} x one 16B col.
    const int srow = tid >> 3;                           // 0..31
    const int scol = tid & 7;                            // 16B col group
    const int swz8 = (scol ^ (srow & 7)) * 8;            // swizzled LDS col (elems)

    u32x4 kr0, kr1, vr0, vr1;                            // staged 16B each (T14)

#define LDREGS(kb_)                                                                     \
    do {                                                                                \
        const ushort* kp = Kh + (size_t)((kb_) + srow) * 64 + scol * 8;                 \
        kr0 = *(const u32x4*)kp;                                                        \
        kr1 = *(const u32x4*)(kp + 32 * 64);                                            \
        const ushort* vp = Vh + (size_t)srow * 2048 + (kb_) + scol * 8;                 \
        vr0 = *(const u32x4*)vp;                                                        \
        vr1 = *(const u32x4*)(vp + (size_t)32 * 2048);                                  \
    } while (0)

#define DSWRITE(buf)                                                                    \
    do {                                                                                \
        ushort* kd = &Ksm[buf][srow * 64 + swz8];                                       \
        *(u32x4*)kd = kr0;                                                              \
        *(u32x4*)(kd + 32 * 64) = kr1;                                                  \
        ushort* vd = &Vsm[buf][srow * 64 + swz8];                                       \
        *(u32x4*)vd = vr0;                                                              \
        *(u32x4*)(vd + 32 * 64) = vr1;                                                  \
    } while (0)

    const int nc = 2 * qt + 2;                           // 64-key chunks for this block
    const int cdiag = 2 * qt + (w >> 1);                 // wave's diagonal chunk

    LDREGS(0);
    DSWRITE(0);
    __syncthreads();

    float mrun = -1e30f, lsum = 0.f;
    f32x16 acc0, acc1;                                   // ctx^T d-tiles 0..31 / 32..63
#pragma unroll
    for (int r = 0; r < 16; ++r) { acc0[r] = 0.f; acc1[r] = 0.f; }

    int cur = 0;
    for (int c = 0; c < nc; ++c) {
        const int kb = c * 64;
        const bool havenext = (c + 1 < nc);
        if (havenext) LDREGS(kb + 64);                   // issue early: hide under compute

        if (!(w < 2 && c == nc - 1)) {                   // w0/1: last chunk fully masked
            const ushort* Kc = &Ksm[cur][0];
            const ushort* Vc = &Vsm[cur][0];

            // ---- QK^T: two 32x32 S-tiles (keys kb..+31, kb+32..+63)
            f32x16 st0, st1;
#pragma unroll
            for (int r = 0; r < 16; ++r) { st0[r] = 0.f; st1[r] = 0.f; }
            __builtin_amdgcn_s_setprio(1);
#pragma unroll
            for (int dc = 0; dc < 4; ++dc) {
                short8 kf0 = *(const short8*)(Kc + l31 * 64 + (((dc * 2 + hi) ^ r7) << 3));
                short8 kf1 = *(const short8*)(Kc + (32 + l31) * 64 + (((dc * 2 + hi) ^ r7) << 3));
                st0 = MFMA32(kf0, qf[dc], st0);
                st1 = MFMA32(kf1, qf[dc], st1);
            }
            __builtin_amdgcn_s_setprio(0);

            // ---- causal mask (diagonal chunk only); key = base + (r&3) + 8*(r>>2)
            if (c == cdiag) {
                const int base0 = kb + (hi << 2);
                const int base1 = kb + 32 + (hi << 2);
#pragma unroll
                for (int r = 0; r < 16; ++r) {
                    int k0 = base0 + ((r & 3) + 8 * (r >> 2));
                    int k1 = base1 + ((r & 3) + 8 * (r >> 2));
                    st0[r] = (k0 <= qrow) ? st0[r] : -1e30f;
                    st1[r] = (k1 <= qrow) ? st1[r] : -1e30f;
                }
            }

            // ---- online softmax (log2 domain), defer-max THR=8
            float tmax = st0[0];
#pragma unroll
            for (int r = 1; r < 16; ++r) tmax = fmaxf(tmax, st0[r]);
#pragma unroll
            for (int r = 0; r < 16; ++r) tmax = fmaxf(tmax, st1[r]);
            tmax = fmaxf(tmax, __shfl_xor(tmax, 32));    // partner holds other half of row

            if (!__all(tmax <= mrun + 8.0f)) {
                float mnew = fmaxf(mrun, tmax);
                float sc = exp2f(mrun - mnew);
#pragma unroll
                for (int r = 0; r < 16; ++r) { acc0[r] *= sc; acc1[r] *= sc; }
                lsum *= sc;
                mrun = mnew;
            }

            float tsum = 0.f;
#pragma unroll
            for (int r = 0; r < 16; ++r) { st0[r] = exp2f(st0[r] - mrun); tsum += st0[r]; }
#pragma unroll
            for (int r = 0; r < 16; ++r) { st1[r] = exp2f(st1[r] - mrun); tsum += st1[r]; }
            lsum += tsum;                                // partner partial merged at end

            // ---- T14: commit staged regs to the other buffer mid-chunk
            // (buf^1 untouched by any wave since the last barrier -> race-free)
            if (havenext) DSWRITE(cur ^ 1);

            // ---- P re-frag in registers + PV (T12; verified round 4)
            // permlane32_swap: vdst[32+i] <-> vsrc[i]; lanes 0-31 receive in vsrc (pb),
            // lanes 32-63 receive in vdst (pa).
#define MAKE_PFRAG(st, kcL, out)                                                        \
    do {                                                                                \
        unsigned c00 = cvtpk(st[8 * kcL + 0], st[8 * kcL + 1]);                         \
        unsigned c01 = cvtpk(st[8 * kcL + 2], st[8 * kcL + 3]);                         \
        unsigned c10 = cvtpk(st[8 * kcL + 4], st[8 * kcL + 5]);                         \
        unsigned c11 = cvtpk(st[8 * kcL + 6], st[8 * kcL + 7]);                         \
        unsigned e0 = hi ? c00 : c10, e1 = hi ? c01 : c11;                              \
        unsigned pa0 = e0, pb0 = e0, pa1 = e1, pb1 = e1;                                \
        asm volatile("v_permlane32_swap_b32 %0, %1" : "+v"(pa0), "+v"(pb0));            \
        asm volatile("v_permlane32_swap_b32 %0, %1" : "+v"(pa1), "+v"(pb1));            \
        unsigned rec0 = hi ? pa0 : pb0;                                                 \
        unsigned rec1 = hi ? pa1 : pb1;                                                 \
        u32x4 fw;                                                                       \
        fw.x = hi ? rec0 : c00;                                                         \
        fw.y = hi ? rec1 : c01;                                                         \
        fw.z = hi ? c10 : rec0;                                                         \
        fw.w = hi ? c11 : rec1;                                                         \
        out = __builtin_bit_cast(short8, fw);                                           \
    } while (0)

            short8 pf;
            MAKE_PFRAG(st0, 0, pf);
            __builtin_amdgcn_s_setprio(1);
            {
                short8 v0 = *(const short8*)(Vc + l31 * 64 + ((hi ^ r7) << 3));
                short8 v1 = *(const short8*)(Vc + (32 + l31) * 64 + ((hi ^ r7) << 3));
                acc0 = MFMA32(v0, pf, acc0);
                acc1 = MFMA32(v1, pf, acc1);
            }
            __builtin_amdgcn_s_setprio(0);
            MAKE_PFRAG(st0, 1, pf);
            __builtin_amdgcn_s_setprio(1);
            {
                short8 v0 = *(const short8*)(Vc + l31 * 64 + (((2 + hi) ^ r7) << 3));
                short8 v1 = *(const short8*)(Vc + (32 + l31) * 64 + (((2 + hi) ^ r7) << 3));
                acc0 = MFMA32(v0, pf, acc0);
                acc1 = MFMA32(v1, pf, acc1);
            }
            __builtin_amdgcn_s_setprio(0);
            MAKE_PFRAG(st1, 0, pf);
            __builtin_amdgcn_s_setprio(1);
            {
                short8 v0 = *(const short8*)(Vc + l31 * 64 + (((4 + hi) ^ r7) << 3));
                short8 v1 = *(const short8*)(Vc + (32 + l31) * 64 + (((4 + hi) ^ r7) << 3));
                acc0 = MFMA32(v0, pf, acc0);
                acc1 = MFMA32(v1, pf, acc1);
            }
            __builtin_amdgcn_s_setprio(0);
            MAKE_PFRAG(st1, 1, pf);
            __builtin_amdgcn_s_setprio(1);
            {
                short8 v0 = *(const short8*)(Vc + l31 * 64 + (((6 + hi) ^ r7) << 3));
                short8 v1 = *(const short8*)(Vc + (32 + l31) * 64 + (((6 + hi) ^ r7) << 3));
                acc0 = MFMA32(v0, pf, acc0);
                acc1 = MFMA32(v1, pf, acc1);
            }
            __builtin_amdgcn_s_setprio(0);
#undef MAKE_PFRAG
        } else {
            if (havenext) DSWRITE(cur ^ 1);              // skip waves still stage
        }

        __syncthreads();
        cur ^= 1;
    }
#undef LDREGS
#undef DSWRITE

    lsum += __shfl_xor(lsum, 32);                        // merge partner halves
    const float inv = 1.f / lsum;
    const int b = bh >> 4, h = bh & 15;
    const size_t tokrow = ((size_t)b * 2048 + qw0 + l31) * 1024 + (size_t)h * 64;

#define WRITE_DT(accv, dt)                                                              \
    do {                                                                                \
        _Pragma("unroll")                                                               \
        for (int q2 = 0; q2 < 4; ++q2) {                                                \
            int d0 = dt * 32 + 8 * q2 + (hi << 2);                                      \
            u16x4 o;                                                                    \
            _Pragma("unroll")                                                           \
            for (int j = 0; j < 4; ++j) o[j] = f2bf(accv[4 * q2 + j] * inv);            \
            *(u16x4*)&CTX[tokrow + d0] = o;                                             \
        }                                                                               \
    } while (0)

    WRITE_DT(acc0, 0);
    WRITE_DT(acc1, 1);
#undef WRITE_DT
}

// ----------------------------------------------------------------------------
extern "C" void kernel_launch(void* const* d_in, const int* in_sizes, int n_in,
                              void* d_out, int out_size, void* d_ws, size_t ws_size,
                              hipStream_t stream) {
    const float* X     = (const float*)d_in[0];   // [2,2048,1024]
    const float* Wqkv  = (const float*)d_in[1];   // [1024,3072]
    const float* bqkv  = (const float*)d_in[2];   // [3072]
    const float* Wproj = (const float*)d_in[3];   // [1024,1024]
    const float* bproj = (const float*)d_in[4];   // [1024]
    float* Out = (float*)d_out;                   // [2,2048,1024] fp32

    // workspace layout (bf16 elements), total ~48 MB
    ushort* Xb     = (ushort*)d_ws;
    ushort* WqkvT  = Xb + (size_t)4096 * 1024;
    ushort* WprojT = WqkvT + (size_t)3072 * 1024;
    ushort* Qb     = WprojT + (size_t)1024 * 1024;  // [b,h,s,d] prescaled
    ushort* Kb     = Qb + (size_t)4096 * 1024;      // [b,h,s,d]
    ushort* VT     = Kb + (size_t)4096 * 1024;      // [b,h,d,s]
    ushort* CTX    = VT + (size_t)4096 * 1024;      // [tok, 1024] merged heads

    cast_x_kernel<<<4096, 256, 0, stream>>>(X, Xb);
    transpose_cast_kernel<<<dim3(48, 16), 256, 0, stream>>>(Wqkv, WqkvT, 1024, 3072);
    transpose_cast_kernel<<<dim3(16, 16), 256, 0, stream>>>(Wproj, WprojT, 1024, 1024);
    gemm_bt_kernel<0><<<dim3(24, 32), 256, 0, stream>>>(Xb, WqkvT, bqkv, Qb, Kb, VT, nullptr,
                                                        4096, 3072, 1024);
    attn_kernel<<<512, 256, 0, stream>>>(Qb, Kb, VT, CTX);
    gemm_bt_kernel<1><<<dim3(8, 32), 256, 0, stream>>>(CTX, WprojT, bproj, nullptr, nullptr,
                                                       nullptr, Out, 4096, 1024, 1024);
}

// Round 10
// 148.648 us; speedup vs baseline: 8.5945x; 1.1335x over previous
//
#include <hip/hip_runtime.h>
#include <hip/hip_bf16.h>

typedef __attribute__((ext_vector_type(8))) short short8;     // 8 bf16 (4 VGPRs) MFMA A/B frag
typedef __attribute__((ext_vector_type(4))) float f32x4;      // 16x16 MFMA C/D frag
typedef __attribute__((ext_vector_type(16))) float f32x16;    // 32x32 MFMA C/D frag
typedef __attribute__((ext_vector_type(4))) unsigned short u16x4;
typedef __attribute__((ext_vector_type(4))) unsigned int u32x4;

#define MFMA16(a, b, c) __builtin_amdgcn_mfma_f32_16x16x32_bf16((a), (b), (c), 0, 0, 0)
#define MFMA32(a, b, c) __builtin_amdgcn_mfma_f32_32x32x16_bf16((a), (b), (c), 0, 0, 0)

__device__ __forceinline__ unsigned short f2bf(float f) {
    union { float f; unsigned u; } v; v.f = f;
    return (unsigned short)((v.u + 0x7fffu + ((v.u >> 16) & 1u)) >> 16);
}

__device__ __forceinline__ unsigned cvtpk(float lo, float hi_) {
    unsigned r;
    asm volatile("v_cvt_pk_bf16_f32 %0, %1, %2" : "=v"(r) : "v"(lo), "v"(hi_));
    return r;
}

// ---------------------------------------------------------------- cast X -> bf16
__global__ void cast_x_kernel(const float* __restrict__ x, ushort* __restrict__ y) {
    int i = blockIdx.x * blockDim.x + threadIdx.x;      // one float4 per thread, exact grid
    float4 v = ((const float4*)x)[i];
    u16x4 o = { f2bf(v.x), f2bf(v.y), f2bf(v.z), f2bf(v.w) };
    *(u16x4*)(y + (size_t)i * 4) = o;
}

// ------------------------------------------- W [K][N] f32 -> WT [N][K] bf16
__global__ void transpose_cast_kernel(const float* __restrict__ W, ushort* __restrict__ WT,
                                      int K, int N) {
    __shared__ ushort t[64][66];                        // 66: odd word stride, conflict-free
    int n0 = blockIdx.x * 64, k0 = blockIdx.y * 64;
    int tn = threadIdx.x & 63, tg = threadIdx.x >> 6;
#pragma unroll
    for (int i = 0; i < 16; ++i) {
        int k = tg * 16 + i;
        t[tn][k] = f2bf(W[(size_t)(k0 + k) * N + n0 + tn]);
    }
    __syncthreads();
#pragma unroll
    for (int i = 0; i < 16; ++i) {
        int nn = tg * 16 + i;
        WT[(size_t)(n0 + nn) * K + k0 + tn] = t[nn][tn];
    }
}

// ---------------------------------------------------------------- GEMM C = A @ BT^T
// A [M][K] bf16 row-major, BT [N][K] bf16 (n-major). 128x128 tile, BK=64, 4 waves.
// MODE 0: QKV epilogue -> scatter Q (prescaled), K, VT (transposed V), bf16.
// MODE 1: proj epilogue -> Out fp32 [M][N].
#define QSCALE 0.18033688011112042f   /* 0.125 * log2(e) */

template <int MODE>
__global__ __launch_bounds__(256)
void gemm_bt_kernel(const ushort* __restrict__ A, const ushort* __restrict__ BT,
                    const float* __restrict__ bias,
                    ushort* __restrict__ Qb, ushort* __restrict__ Kb,
                    ushort* __restrict__ VT, float* __restrict__ Out,
                    int M, int N, int K) {
    __shared__ ushort Asm[128 * 64];
    __shared__ ushort Bsm[128 * 64];
    const int lane = threadIdx.x & 63;
    const int wv = threadIdx.x >> 6;
    const int l15 = lane & 15, lg = lane >> 4;
    const int rm = (wv >> 1) * 64, cn = (wv & 1) * 64;  // wave's 64x64 sub-tile
    const int row0 = blockIdx.y * 128, col0 = blockIdx.x * 128;

    const char* Agb = (const char*)(A + (size_t)row0 * K);
    const char* Bgb = (const char*)(BT + (size_t)col0 * K);
    const size_t rowbytes = (size_t)K * 2;

    f32x4 acc[4][4];
#pragma unroll
    for (int mi = 0; mi < 4; ++mi)
#pragma unroll
        for (int ni = 0; ni < 4; ++ni) acc[mi][ni] = f32x4{0.f, 0.f, 0.f, 0.f};

    const int grow_l = (lane >> 3);          // 0..7 within 8-row chunk
    const int gcol_l = (lane & 7) * 16;      // byte within 128B row

    for (int k0 = 0; k0 < K; k0 += 64) {
#pragma unroll
        for (int c = 0; c < 4; ++c) {
            int chunk = wv * 4 + c;                       // 16 chunks of 1KB
            size_t go = (size_t)(chunk * 8 + grow_l) * rowbytes + (size_t)k0 * 2 + gcol_l;
            int lo = chunk * 1024 + lane * 16;
            __builtin_amdgcn_global_load_lds(
                (const __attribute__((address_space(1))) void*)(Agb + go),
                (__attribute__((address_space(3))) void*)((char*)Asm + lo), 16, 0, 0);
            __builtin_amdgcn_global_load_lds(
                (const __attribute__((address_space(1))) void*)(Bgb + go),
                (__attribute__((address_space(3))) void*)((char*)Bsm + lo), 16, 0, 0);
        }
        __syncthreads();
#pragma unroll
        for (int ks = 0; ks < 2; ++ks) {
            short8 af[4], bf[4];
#pragma unroll
            for (int mi = 0; mi < 4; ++mi)
                af[mi] = *(const short8*)&Asm[(rm + mi * 16 + l15) * 64 + ks * 32 + lg * 8];
#pragma unroll
            for (int ni = 0; ni < 4; ++ni)
                bf[ni] = *(const short8*)&Bsm[(cn + ni * 16 + l15) * 64 + ks * 32 + lg * 8];
#pragma unroll
            for (int mi = 0; mi < 4; ++mi)
#pragma unroll
                for (int ni = 0; ni < 4; ++ni)
                    acc[mi][ni] = MFMA16(af[mi], bf[ni], acc[mi][ni]);
        }
        __syncthreads();
    }

    // Epilogue. D layout: lane holds D[(lg)*4+j][l15] (row=M dim, col=N dim).
    if (MODE == 0) {
        const int sect = col0 >> 10;   // 0=q 1=k 2=v, uniform per block (128 | 1024)
#pragma unroll
        for (int ni = 0; ni < 4; ++ni) {
            int col = col0 + cn + ni * 16 + l15;
            float bv = bias[col];
            int dcol = col & 1023, h = dcol >> 6, dd = dcol & 63;
#pragma unroll
            for (int mi = 0; mi < 4; ++mi) {
                int mrow0 = row0 + rm + mi * 16 + lg * 4;
                if (sect == 2) {
                    int b = mrow0 >> 11, s = mrow0 & 2047;   // 4 consecutive s, same b
                    u16x4 o;
#pragma unroll
                    for (int j = 0; j < 4; ++j) o[j] = f2bf(acc[mi][ni][j] + bv);
                    *(u16x4*)&VT[((size_t)((b << 4) + h) * 64 + dd) * 2048 + s] = o;
                } else {
                    ushort* dst = sect ? Kb : Qb;
                    float sc = sect ? 1.f : QSCALE;
#pragma unroll
                    for (int j = 0; j < 4; ++j) {
                        int tok = mrow0 + j;
                        int b = tok >> 11, s = tok & 2047;
                        dst[((size_t)((b << 4) + h) * 2048 + s) * 64 + dd] =
                            f2bf((acc[mi][ni][j] + bv) * sc);
                    }
                }
            }
        }
    } else {
#pragma unroll
        for (int ni = 0; ni < 4; ++ni) {
            int col = col0 + cn + ni * 16 + l15;
            float bv = bias[col];
#pragma unroll
            for (int mi = 0; mi < 4; ++mi) {
                int mrow0 = row0 + rm + mi * 16 + lg * 4;
#pragma unroll
                for (int j = 0; j < 4; ++j)
                    Out[(size_t)(mrow0 + j) * N + col] = acc[mi][ni][j] + bv;
            }
        }
    }
}

// ---------------------------------------------------------------- causal flash attention v8
// = v7 + ILP fixes + complementary pairing:
//  - QK: all 8 K-fragment ds_reads issued back-to-back into regs, THEN 8 MFMAs
//    (was read2->mfma2 pairs = serialized lgkmcnt waits).
//  - V: all 8 V-fragment ds_reads hoisted to just after the mask; latency hides
//    under softmax VALU; PV MFMAs run register-only.
//  - qt = (jj>>5)&1 ? (jj&15) : 15-(jj&15): co-resident blocks (id, id+256) get
//    complementary heavy/light tiles (was same-qt -> diagonal CUs 16x overloaded).
// Retained: T14 reg-staged dbuf (1 barrier/chunk), T12 cvt_pk+permlane re-frag,
// T13 defer-max, T5 setprio, XOR-swizzled LDS, w0/1 final-chunk skip.
__global__ __launch_bounds__(256)
void attn_kernel(const ushort* __restrict__ Qb, const ushort* __restrict__ Kb,
                 const ushort* __restrict__ VT, ushort* __restrict__ CTX) {
    __shared__ __align__(16) ushort Ksm[2][64 * 64];    // [key][d], 16B-slot XOR-swizzled
    __shared__ __align__(16) ushort Vsm[2][64 * 64];    // [d][key], 16B-slot XOR-swizzled

    const int tid = threadIdx.x;
    const int lane = tid & 63;
    const int w = tid >> 6;
    const int l31 = lane & 31;
    const int hi = lane >> 5;                            // 0/1
    const int r7 = l31 & 7;

    // block remap: 512 blocks = 8 xcd x (4 bh x 16 qt); complementary pairing.
    const int id = blockIdx.x;
    const int xcd = id & 7, jj = id >> 3;
    const int bh = (xcd << 2) + (jj >> 4);               // 4 heads per XCD -> K/V L2-resident
    const int qt = ((jj >> 5) & 1) ? (jj & 15) : 15 - (jj & 15);
    const int qw0 = qt * 128 + w * 32;                   // wave's 32 q-rows
    const int qrow = qw0 + l31;

    const ushort* Qh = Qb + (size_t)bh * 2048 * 64;
    const ushort* Kh = Kb + (size_t)bh * 2048 * 64;
    const ushort* Vh = VT + (size_t)bh * 64 * 2048;

    // Q fragments: B-operand of QK mfma: lane needs Q[qrow][dc*16+hi*8..+7]
    short8 qf[4];
#pragma unroll
    for (int dc = 0; dc < 4; ++dc)
        qf[dc] = *(const short8*)&Qh[(size_t)qrow * 64 + dc * 16 + hi * 8];

    // staging geometry: 256 threads, each owns rows {srow, srow+32} x one 16B col.
    const int srow = tid >> 3;                           // 0..31
    const int scol = tid & 7;                            // 16B col group
    const int swz8 = (scol ^ (srow & 7)) * 8;            // swizzled LDS col (elems)

    u32x4 kr0, kr1, vr0, vr1;                            // staged 16B each (T14)

#define LDREGS(kb_)                                                                     \
    do {                                                                                \
        const ushort* kp = Kh + (size_t)((kb_) + srow) * 64 + scol * 8;                 \
        kr0 = *(const u32x4*)kp;                                                        \
        kr1 = *(const u32x4*)(kp + 32 * 64);                                            \
        const ushort* vp = Vh + (size_t)srow * 2048 + (kb_) + scol * 8;                 \
        vr0 = *(const u32x4*)vp;                                                        \
        vr1 = *(const u32x4*)(vp + (size_t)32 * 2048);                                  \
    } while (0)

#define DSWRITE(buf)                                                                    \
    do {                                                                                \
        ushort* kd = &Ksm[buf][srow * 64 + swz8];                                       \
        *(u32x4*)kd = kr0;                                                              \
        *(u32x4*)(kd + 32 * 64) = kr1;                                                  \
        ushort* vd = &Vsm[buf][srow * 64 + swz8];                                       \
        *(u32x4*)vd = vr0;                                                              \
        *(u32x4*)(vd + 32 * 64) = vr1;                                                  \
    } while (0)

    const int nc = 2 * qt + 2;                           // 64-key chunks for this block
    const int cdiag = 2 * qt + (w >> 1);                 // wave's diagonal chunk

    LDREGS(0);
    DSWRITE(0);
    __syncthreads();

    float mrun = -1e30f, lsum = 0.f;
    f32x16 acc0, acc1;                                   // ctx^T d-tiles 0..31 / 32..63
#pragma unroll
    for (int r = 0; r < 16; ++r) { acc0[r] = 0.f; acc1[r] = 0.f; }

    int cur = 0;
    for (int c = 0; c < nc; ++c) {
        const int kb = c * 64;
        const bool havenext = (c + 1 < nc);
        if (havenext) LDREGS(kb + 64);                   // issue early: hide under compute

        if (!(w < 2 && c == nc - 1)) {                   // w0/1: last chunk fully masked
            const ushort* Kc = &Ksm[cur][0];
            const ushort* Vc = &Vsm[cur][0];

            // ---- K fragments: 8 ds_reads back-to-back (latencies overlap)
            short8 kf0[4], kf1[4];
#pragma unroll
            for (int dc = 0; dc < 4; ++dc) {
                kf0[dc] = *(const short8*)(Kc + l31 * 64 + (((dc * 2 + hi) ^ r7) << 3));
                kf1[dc] = *(const short8*)(Kc + (32 + l31) * 64 + (((dc * 2 + hi) ^ r7) << 3));
            }

            // ---- QK^T: two 32x32 S-tiles (keys kb..+31, kb+32..+63)
            f32x16 st0, st1;
#pragma unroll
            for (int r = 0; r < 16; ++r) { st0[r] = 0.f; st1[r] = 0.f; }
            __builtin_amdgcn_s_setprio(1);
#pragma unroll
            for (int dc = 0; dc < 4; ++dc) {
                st0 = MFMA32(kf0[dc], qf[dc], st0);
                st1 = MFMA32(kf1[dc], qf[dc], st1);
            }
            __builtin_amdgcn_s_setprio(0);

            // ---- causal mask (diagonal chunk only); key = base + (r&3) + 8*(r>>2)
            if (c == cdiag) {
                const int base0 = kb + (hi << 2);
                const int base1 = kb + 32 + (hi << 2);
#pragma unroll
                for (int r = 0; r < 16; ++r) {
                    int k0 = base0 + ((r & 3) + 8 * (r >> 2));
                    int k1 = base1 + ((r & 3) + 8 * (r >> 2));
                    st0[r] = (k0 <= qrow) ? st0[r] : -1e30f;
                    st1[r] = (k1 <= qrow) ? st1[r] : -1e30f;
                }
            }

            // ---- V fragments: 8 ds_reads issued now; latency hides under softmax.
            // vg*[g] pairs with (st tile, k-chunk): g=0:(st0,kc0) g=1:(st0,kc1)
            // g=2:(st1,kc0) g=3:(st1,kc1); col factor = 2g+hi.
            short8 vg0[4], vg1[4];
#pragma unroll
            for (int g = 0; g < 4; ++g) {
                vg0[g] = *(const short8*)(Vc + l31 * 64 + (((2 * g + hi) ^ r7) << 3));
                vg1[g] = *(const short8*)(Vc + (32 + l31) * 64 + (((2 * g + hi) ^ r7) << 3));
            }

            // ---- online softmax (log2 domain), defer-max THR=8
            float tmax = st0[0];
#pragma unroll
            for (int r = 1; r < 16; ++r) tmax = fmaxf(tmax, st0[r]);
#pragma unroll
            for (int r = 0; r < 16; ++r) tmax = fmaxf(tmax, st1[r]);
            tmax = fmaxf(tmax, __shfl_xor(tmax, 32));    // partner holds other half of row

            if (!__all(tmax <= mrun + 8.0f)) {
                float mnew = fmaxf(mrun, tmax);
                float sc = exp2f(mrun - mnew);
#pragma unroll
                for (int r = 0; r < 16; ++r) { acc0[r] *= sc; acc1[r] *= sc; }
                lsum *= sc;
                mrun = mnew;
            }

            float tsum = 0.f;
#pragma unroll
            for (int r = 0; r < 16; ++r) { st0[r] = exp2f(st0[r] - mrun); tsum += st0[r]; }
#pragma unroll
            for (int r = 0; r < 16; ++r) { st1[r] = exp2f(st1[r] - mrun); tsum += st1[r]; }
            lsum += tsum;                                // partner partial merged at end

            // ---- T14: commit staged regs to the other buffer mid-chunk
            if (havenext) DSWRITE(cur ^ 1);

            // ---- P re-frag in registers + PV (T12; verified round 4)
#define MAKE_PFRAG(st, kcL, out)                                                        \
    do {                                                                                \
        unsigned c00 = cvtpk(st[8 * kcL + 0], st[8 * kcL + 1]);                         \
        unsigned c01 = cvtpk(st[8 * kcL + 2], st[8 * kcL + 3]);                         \
        unsigned c10 = cvtpk(st[8 * kcL + 4], st[8 * kcL + 5]);                         \
        unsigned c11 = cvtpk(st[8 * kcL + 6], st[8 * kcL + 7]);                         \
        unsigned e0 = hi ? c00 : c10, e1 = hi ? c01 : c11;                              \
        unsigned pa0 = e0, pb0 = e0, pa1 = e1, pb1 = e1;                                \
        asm volatile("v_permlane32_swap_b32 %0, %1" : "+v"(pa0), "+v"(pb0));            \
        asm volatile("v_permlane32_swap_b32 %0, %1" : "+v"(pa1), "+v"(pb1));            \
        unsigned rec0 = hi ? pa0 : pb0;                                                 \
        unsigned rec1 = hi ? pa1 : pb1;                                                 \
        u32x4 fw;                                                                       \
        fw.x = hi ? rec0 : c00;                                                         \
        fw.y = hi ? rec1 : c01;                                                         \
        fw.z = hi ? c10 : rec0;                                                         \
        fw.w = hi ? c11 : rec1;                                                         \
        out = __builtin_bit_cast(short8, fw);                                           \
    } while (0)

            short8 pf;
            __builtin_amdgcn_s_setprio(1);
            MAKE_PFRAG(st0, 0, pf);
            acc0 = MFMA32(vg0[0], pf, acc0);
            acc1 = MFMA32(vg1[0], pf, acc1);
            MAKE_PFRAG(st0, 1, pf);
            acc0 = MFMA32(vg0[1], pf, acc0);
            acc1 = MFMA32(vg1[1], pf, acc1);
            MAKE_PFRAG(st1, 0, pf);
            acc0 = MFMA32(vg0[2], pf, acc0);
            acc1 = MFMA32(vg1[2], pf, acc1);
            MAKE_PFRAG(st1, 1, pf);
            acc0 = MFMA32(vg0[3], pf, acc0);
            acc1 = MFMA32(vg1[3], pf, acc1);
            __builtin_amdgcn_s_setprio(0);
#undef MAKE_PFRAG
        } else {
            if (havenext) DSWRITE(cur ^ 1);              // skip waves still stage
        }

        __syncthreads();
        cur ^= 1;
    }
#undef LDREGS
#undef DSWRITE

    lsum += __shfl_xor(lsum, 32);                        // merge partner halves
    const float inv = 1.f / lsum;
    const int b = bh >> 4, h = bh & 15;
    const size_t tokrow = ((size_t)b * 2048 + qw0 + l31) * 1024 + (size_t)h * 64;

#define WRITE_DT(accv, dt)                                                              \
    do {                                                                                \
        _Pragma("unroll")                                                               \
        for (int q2 = 0; q2 < 4; ++q2) {                                                \
            int d0 = dt * 32 + 8 * q2 + (hi << 2);                                      \
            u16x4 o;                                                                    \
            _Pragma("unroll")                                                           \
            for (int j = 0; j < 4; ++j) o[j] = f2bf(accv[4 * q2 + j] * inv);            \
            *(u16x4*)&CTX[tokrow + d0] = o;                                             \
        }                                                                               \
    } while (0)

    WRITE_DT(acc0, 0);
    WRITE_DT(acc1, 1);
#undef WRITE_DT
}

// ----------------------------------------------------------------------------
extern "C" void kernel_launch(void* const* d_in, const int* in_sizes, int n_in,
                              void* d_out, int out_size, void* d_ws, size_t ws_size,
                              hipStream_t stream) {
    const float* X     = (const float*)d_in[0];   // [2,2048,1024]
    const float* Wqkv  = (const float*)d_in[1];   // [1024,3072]
    const float* bqkv  = (const float*)d_in[2];   // [3072]
    const float* Wproj = (const float*)d_in[3];   // [1024,1024]
    const float* bproj = (const float*)d_in[4];   // [1024]
    float* Out = (float*)d_out;                   // [2,2048,1024] fp32

    // workspace layout (bf16 elements), total ~48 MB
    ushort* Xb     = (ushort*)d_ws;
    ushort* WqkvT  = Xb + (size_t)4096 * 1024;
    ushort* WprojT = WqkvT + (size_t)3072 * 1024;
    ushort* Qb     = WprojT + (size_t)1024 * 1024;  // [b,h,s,d] prescaled
    ushort* Kb     = Qb + (size_t)4096 * 1024;      // [b,h,s,d]
    ushort* VT     = Kb + (size_t)4096 * 1024;      // [b,h,d,s]
    ushort* CTX    = VT + (size_t)4096 * 1024;      // [tok, 1024] merged heads

    cast_x_kernel<<<4096, 256, 0, stream>>>(X, Xb);
    transpose_cast_kernel<<<dim3(48, 16), 256, 0, stream>>>(Wqkv, WqkvT, 1024, 3072);
    transpose_cast_kernel<<<dim3(16, 16), 256, 0, stream>>>(Wproj, WprojT, 1024, 1024);
    gemm_bt_kernel<0><<<dim3(24, 32), 256, 0, stream>>>(Xb, WqkvT, bqkv, Qb, Kb, VT, nullptr,
                                                        4096, 3072, 1024);
    attn_kernel<<<512, 256, 0, stream>>>(Qb, Kb, VT, CTX);
    gemm_bt_kernel<1><<<dim3(8, 32), 256, 0, stream>>>(CTX, WprojT, bproj, nullptr, nullptr,
                                                       nullptr, Out, 4096, 1024, 1024);
}